// Round 4
// baseline (30682.083 us; speedup 1.0000x reference)
//
#include <hip/hip_runtime.h>
#include <cstdint>

// ---- problem dims (fixed by reference) ----
#define Hdim 512
#define Bdim 128
#define Tdim 512
#define FUT  32
#define TT   (Tdim + FUT)   // 544
#define NBLK 256
#define NTHR 256
#define HB   (Hdim * Bdim)

// ---- ws layout (float offsets) ----
#define WP1_OFF   0                                  // [512][512] float4 (gate-packed W_hh1)
#define WP2I_OFF  (WP1_OFF  + Hdim*Hdim*4)           // W_ih2 packed
#define WP2H_OFF  (WP2I_OFF + Hdim*Hdim*4)           // W_hh2 packed
#define B1P_OFF   (WP2H_OFF + Hdim*Hdim*4)           // [512] float4 bias1 (b_ih1+b_hh1)
#define B2P_OFF   (B1P_OFF  + Hdim*4)
#define WX1_OFF   (B2P_OFF  + Hdim*4)                // [512] float4 W_ih1 per gate
#define XT_OFF    (WX1_OFF  + Hdim*4)                // xT[t][b]  (512*128)
#define H1_OFF    (XT_OFF   + Tdim*Bdim)             // 2 ping-pong [512][128]; h1(s) in buf[s&1]
#define H2_OFF    (H1_OFF   + 2*HB)                  // h2(s) in buf[(s+1)&1]
#define ZERO_OFF  (H2_OFF   + 2*HB)                  // [128] zeros (volatile-read defeats SMEM promo)
#define ARR_OFF   (ZERO_OFF + Bdim)                  // [256] arrive flags (uint)
#define WS_FLOATS (ARR_OFF  + NBLK + 16)

__device__ __forceinline__ float sigm(float v) { return 1.0f / (1.0f + __expf(-v)); }
__device__ __forceinline__ float tanh_fast(float v) {
    v = fminf(fmaxf(v, -20.0f), 20.0f);
    float e = __expf(2.0f * v);
    return (e - 1.0f) / (e + 1.0f);
}

// ---- device-coherent (agent-scope, relaxed) accessors ----
__device__ __forceinline__ unsigned long long cohload64(const unsigned long long* p) {
    return __hip_atomic_load(p, __ATOMIC_RELAXED, __HIP_MEMORY_SCOPE_AGENT);
}
__device__ __forceinline__ float cohloadf(const float* p) {
    return __hip_atomic_load(p, __ATOMIC_RELAXED, __HIP_MEMORY_SCOPE_AGENT);
}
__device__ __forceinline__ void cohstoref(float* p, float v) {
    __hip_atomic_store(p, v, __ATOMIC_RELAXED, __HIP_MEMORY_SCOPE_AGENT);
}

// ---------- flat fence-free grid barrier: every block polls all 256 flags ----------
// Release: __syncthreads drains each wave's vmcnt -> coherent h-stores are LLC-visible
// before the arrive-flag store. Acquire: h-reads are agent-scope (read-through).
__device__ __forceinline__ void grid_barrier(unsigned* arr, unsigned phase) {
    __syncthreads();
    if (threadIdx.x == 0)
        __hip_atomic_store(&arr[blockIdx.x], phase, __ATOMIC_RELAXED, __HIP_MEMORY_SCOPE_AGENT);
    while (__hip_atomic_load(&arr[threadIdx.x], __ATOMIC_RELAXED, __HIP_MEMORY_SCOPE_AGENT) < phase)
        __builtin_amdgcn_s_sleep(1);
    __syncthreads();
}

// ---------- one staged pass over a 512-vector h: up to 2 gate-matrices + out-dot ----------
// hsrc: [512][128] transposed h (device-coherent).
// wgA/wgB: GLOBAL gate-packed per-unit weights (wave-uniform address + zoff keeps them VMEM,
//          L2-resident; vmcnt-counted -> independent of the ds_read lgkmcnt pipeline).
template<bool WA, bool WB, bool WO>
__device__ __forceinline__ void pass_fn(const float* hsrc,
                                        const float4* wgA, const float4* wgB,
                                        const float* wout_lds,
                                        int half, int lane, int tid, int zoff,
                                        float4& accA, float4& accB, float& oacc,
                                        float* hlds) {
    const unsigned long long* src = (const unsigned long long*)hsrc + half * 32; // 64-float half
    unsigned long long pre[16];
    #pragma unroll
    for (int p = 0; p < 16; ++p) {
        int idx = p * 256 + tid, r = idx >> 5, c = idx & 31;
        pre[p] = cohload64(src + (size_t)r * 64 + c);
    }
    for (int kc = 0; kc < Hdim; kc += 128) {
        __syncthreads();                               // prev readers of hlds done
        #pragma unroll
        for (int p = 0; p < 16; ++p)
            ((unsigned long long*)hlds)[p * 256 + tid] = pre[p];
        __syncthreads();                               // staging visible
        if (kc + 128 < Hdim) {                         // prefetch next h chunk during compute
            #pragma unroll
            for (int p = 0; p < 16; ++p) {
                int idx = p * 256 + tid, r = idx >> 5, c = idx & 31;
                pre[p] = cohload64(src + (size_t)(kc + 128 + r) * 64 + c);
            }
        }
        // weights: register ping-pong (2x4 float4 per stream in flight) to hide L2 latency
        float4 a0[4], a1[4], b0[4], b1[4];
        #pragma unroll
        for (int j = 0; j < 4; ++j) {
            if (WA) a0[j] = wgA[kc + j + zoff];
            if (WB) b0[j] = wgB[kc + j + zoff];
        }
        #pragma unroll
        for (int kk = 0; kk < 128; kk += 8) {
            #pragma unroll
            for (int j = 0; j < 4; ++j) {
                if (WA) a1[j] = wgA[kc + kk + 4 + j + zoff];
                if (WB) b1[j] = wgB[kc + kk + 4 + j + zoff];
            }
            #pragma unroll
            for (int j = 0; j < 4; ++j) {
                float hv = hlds[(kk + j) * 64 + lane];      // 2 lanes/bank: free
                if (WA) { accA.x = fmaf(a0[j].x, hv, accA.x); accA.y = fmaf(a0[j].y, hv, accA.y);
                          accA.z = fmaf(a0[j].z, hv, accA.z); accA.w = fmaf(a0[j].w, hv, accA.w); }
                if (WB) { accB.x = fmaf(b0[j].x, hv, accB.x); accB.y = fmaf(b0[j].y, hv, accB.y);
                          accB.z = fmaf(b0[j].z, hv, accB.z); accB.w = fmaf(b0[j].w, hv, accB.w); }
                if (WO) oacc = fmaf(wout_lds[kc + kk + j], hv, oacc);
            }
            if (kk + 8 < 128) {                            // folds at compile time (full unroll)
                #pragma unroll
                for (int j = 0; j < 4; ++j) {
                    if (WA) a0[j] = wgA[kc + kk + 8 + j + zoff];
                    if (WB) b0[j] = wgB[kc + kk + 8 + j + zoff];
                }
            }
            #pragma unroll
            for (int j = 0; j < 4; ++j) {
                float hv = hlds[(kk + 4 + j) * 64 + lane];
                if (WA) { accA.x = fmaf(a1[j].x, hv, accA.x); accA.y = fmaf(a1[j].y, hv, accA.y);
                          accA.z = fmaf(a1[j].z, hv, accA.z); accA.w = fmaf(a1[j].w, hv, accA.w); }
                if (WB) { accB.x = fmaf(b1[j].x, hv, accB.x); accB.y = fmaf(b1[j].y, hv, accB.y);
                          accB.z = fmaf(b1[j].z, hv, accB.z); accB.w = fmaf(b1[j].w, hv, accB.w); }
                if (WO) oacc = fmaf(wout_lds[kc + kk + 4 + j], hv, oacc);
            }
        }
    }
}

// ---------- out-dot for future phase ----------
__device__ __forceinline__ float outdot(const float* __restrict__ h2, int half, int lane, int tid,
                                        float* hlds, const float* wout_lds) {
    float acc = 0.0f;
    const float4* src = (const float4*)h2 + half * 16;
    for (int kc = 0; kc < Hdim; kc += 128) {
        __syncthreads();
        #pragma unroll
        for (int p = 0; p < 8; ++p) {
            int idx = p * 256 + tid, r = idx >> 4, c = idx & 15;
            ((float4*)hlds)[idx] = src[(size_t)(kc + r) * 32 + c];
        }
        __syncthreads();
        #pragma unroll 8
        for (int kk = 0; kk < 128; ++kk)
            acc = fmaf(hlds[kk * 64 + lane], wout_lds[kc + kk], acc);
    }
    return acc;
}

// ---------- prep: pack weights gate-major, transpose x, zero state/flags ----------
__global__ void lstm_prep(const float* __restrict__ x,
                          const float* __restrict__ W_ih1, const float* __restrict__ W_hh1,
                          const float* __restrict__ b_ih1, const float* __restrict__ b_hh1,
                          const float* __restrict__ W_ih2, const float* __restrict__ W_hh2,
                          const float* __restrict__ b_ih2, const float* __restrict__ b_hh2,
                          float* __restrict__ ws) {
    int i = blockIdx.x * blockDim.x + threadIdx.x;
    if (i < Hdim * Hdim) {
        int u = i >> 9, k = i & (Hdim - 1);
        float4 w1, w2i, w2h;
        w1.x  = W_hh1[(0 * Hdim + u) * Hdim + k];  w1.y  = W_hh1[(1 * Hdim + u) * Hdim + k];
        w1.z  = W_hh1[(2 * Hdim + u) * Hdim + k];  w1.w  = W_hh1[(3 * Hdim + u) * Hdim + k];
        w2i.x = W_ih2[(0 * Hdim + u) * Hdim + k];  w2i.y = W_ih2[(1 * Hdim + u) * Hdim + k];
        w2i.z = W_ih2[(2 * Hdim + u) * Hdim + k];  w2i.w = W_ih2[(3 * Hdim + u) * Hdim + k];
        w2h.x = W_hh2[(0 * Hdim + u) * Hdim + k];  w2h.y = W_hh2[(1 * Hdim + u) * Hdim + k];
        w2h.z = W_hh2[(2 * Hdim + u) * Hdim + k];  w2h.w = W_hh2[(3 * Hdim + u) * Hdim + k];
        ((float4*)(ws + WP1_OFF))[i]  = w1;
        ((float4*)(ws + WP2I_OFF))[i] = w2i;
        ((float4*)(ws + WP2H_OFF))[i] = w2h;
    }
    if (i < Hdim) {
        float4 bb1 = { b_ih1[i] + b_hh1[i],               b_ih1[Hdim+i] + b_hh1[Hdim+i],
                       b_ih1[2*Hdim+i] + b_hh1[2*Hdim+i], b_ih1[3*Hdim+i] + b_hh1[3*Hdim+i] };
        float4 bb2 = { b_ih2[i] + b_hh2[i],               b_ih2[Hdim+i] + b_hh2[Hdim+i],
                       b_ih2[2*Hdim+i] + b_hh2[2*Hdim+i], b_ih2[3*Hdim+i] + b_hh2[3*Hdim+i] };
        float4 wx  = { W_ih1[i], W_ih1[Hdim+i], W_ih1[2*Hdim+i], W_ih1[3*Hdim+i] };
        ((float4*)(ws + B1P_OFF))[i] = bb1;
        ((float4*)(ws + B2P_OFF))[i] = bb2;
        ((float4*)(ws + WX1_OFF))[i] = wx;
    }
    if (i < Tdim * Bdim) {
        int t = i >> 7, b = i & 127;
        ws[XT_OFF + i] = x[b * Tdim + t];
        ws[H1_OFF + i] = 0.0f;
        ws[H2_OFF + i] = 0.0f;
    }
    if (i < Bdim) ws[ZERO_OFF + i] = 0.0f;
    if (i < NBLK + 16)
        ((unsigned*)(ws + ARR_OFF))[i] = 0u;
}

// ---------- persistent main kernel ----------
__global__ __launch_bounds__(NTHR) void lstm_main(float* ws,
                                                  const float* __restrict__ Wout,
                                                  const float* __restrict__ bout,
                                                  float* __restrict__ out) {
    const int tid  = threadIdx.x;
    const int bid  = blockIdx.x;
    const int w    = tid >> 6;                  // wave 0..3 = local unit
    const int lane = tid & 63;
    const int ug   = bid >> 1;                  // unit group 0..127
    const int half = bid & 1;                   // batch half
    const int u    = __builtin_amdgcn_readfirstlane(ug * 4 + w);
    const int bcol = half * 64 + lane;
    const bool douter = (bid < 2);

    __shared__ float  hlds[128 * 64];           // 32 KB h staging
    __shared__ float  wout_lds[Hdim];           // 2 KB
    __shared__ float  partial[4][64];           // 1 KB

    unsigned* arr = (unsigned*)(ws + ARR_OFF);
    float* h1b0 = ws + H1_OFF;                  // h1(s) -> h1b[s&1]
    float* h1b1 = ws + H1_OFF + HB;
    float* h2b0 = ws + H2_OFF;                  // h2(s) -> h2b[(s+1)&1]
    float* h2b1 = ws + H2_OFF + HB;

    // runtime zero (unprovable by compiler) -> keeps weight loads on the VMEM path
    const int zoff = (int)((const volatile float*)(ws + ZERO_OFF))[lane & 63];

    wout_lds[tid]       = Wout[tid];
    wout_lds[256 + tid] = Wout[256 + tid];

    // weights stay in GLOBAL (L2-resident; no fences ever invalidate them now)
    const float4* wg1  = (const float4*)(ws + WP1_OFF)  + (size_t)u * Hdim;
    const float4* wg2i = (const float4*)(ws + WP2I_OFF) + (size_t)u * Hdim;
    const float4* wg2h = (const float4*)(ws + WP2H_OFF) + (size_t)u * Hdim;
    const float4 bias1 = ((const float4*)(ws + B1P_OFF))[u];
    const float4 bias2 = ((const float4*)(ws + B2P_OFF))[u];
    const float4 wx1   = ((const float4*)(ws + WX1_OFF))[u];
    const float  bout0 = bout[0];

    float c1 = 0.0f, c2 = 0.0f;
    float4 dummy = {0.0f, 0.0f, 0.0f, 0.0f};
    unsigned phase = 0;

    // ---- pre-phase: C1(0) (h1(-1)=0 -> no matvec), publish h1(0) into buf0
    {
        float xv = ws[XT_OFF + bcol];
        float4 a1 = { fmaf(wx1.x, xv, bias1.x), fmaf(wx1.y, xv, bias1.y),
                      fmaf(wx1.z, xv, bias1.z), fmaf(wx1.w, xv, bias1.w) };
        float i1 = sigm(a1.x), f1 = sigm(a1.y), g1 = tanh_fast(a1.z), o1 = sigm(a1.w);
        c1 = fmaf(f1, c1, i1 * g1);
        cohstoref(&h1b0[(size_t)u * Bdim + bcol], o1 * tanh_fast(c1));
    }
    grid_barrier(arr, ++phase);

    // ---- main pipelined phases t=0..510: C1(t+1) + C2(t) (+ O(t-1) on blocks 0/1)
    for (int t = 0; t < 511; ++t) {
        const float* h1cur = (t & 1) ? h1b1 : h1b0;            // h1(t)
        float*       h1nxt = (t & 1) ? h1b0 : h1b1;            // h1(t+1)
        const float* h2prv = (t & 1) ? h2b1 : h2b0;            // h2(t-1)
        float*       h2nxt = (t & 1) ? h2b0 : h2b1;            // h2(t)

        float xv = ws[XT_OFF + (t + 1) * Bdim + bcol];
        float4 a1 = { fmaf(wx1.x, xv, bias1.x), fmaf(wx1.y, xv, bias1.y),
                      fmaf(wx1.z, xv, bias1.z), fmaf(wx1.w, xv, bias1.w) };
        float4 a2 = bias2;
        float oacc = 0.0f;

        // h1(t) staged once: feeds C1(t+1) (wg1) and C2(t)-ih (wg2i)
        pass_fn<true, true, false>(h1cur, wg1, wg2i, wout_lds, half, lane, tid, zoff,
                                   a1, a2, oacc, hlds);
        // h2(t-1) staged once: feeds C2(t)-hh
        pass_fn<true, false, false>(h2prv, wg2h, wg2h, wout_lds, half, lane, tid, zoff,
                                    a2, dummy, oacc, hlds);

        float i1 = sigm(a1.x), f1 = sigm(a1.y), g1 = tanh_fast(a1.z), o1 = sigm(a1.w);
        c1 = fmaf(f1, c1, i1 * g1);
        cohstoref(&h1nxt[(size_t)u * Bdim + bcol], o1 * tanh_fast(c1));
        float i2 = sigm(a2.x), f2 = sigm(a2.y), g2 = tanh_fast(a2.z), o2 = sigm(a2.w);
        c2 = fmaf(f2, c2, i2 * g2);
        float h2v = o2 * tanh_fast(c2);
        cohstoref(&h2nxt[(size_t)u * Bdim + bcol], h2v);

        grid_barrier(arr, ++phase);

        // ---- O(t) quick-dot on blocks 0/1 (h2(t) just published; coherent reads)
        if (douter) {
            float acc = 0.0f;
            const float* hb = h2nxt + bcol;
            const int k0 = w * 128;
            #pragma unroll 8
            for (int kk = 0; kk < 128; ++kk)
                acc = fmaf(cohloadf(&hb[(size_t)(k0 + kk) * Bdim]), wout_lds[k0 + kk], acc);
            partial[w][lane] = acc;
            __syncthreads();
            if (w == 0) {
                out[(size_t)bcol * TT + t] = partial[0][lane] + partial[1][lane]
                                           + partial[2][lane] + partial[3][lane] + bout0;
            }
            __syncthreads();
        }
    }

    // ---- phase 511: C2(511)
    {
        const float* h1cur = h1b1;                             // h1(511)
        const float* h2prv = h2b1;                             // h2(510)
        float*       h2nxt = h2b0;                             // h2(511)
        float4 a2 = bias2;
        float oacc = 0.0f;
        pass_fn<true, false, false>(h1cur, wg2i, wg2i, wout_lds, half, lane, tid, zoff,
                                    a2, dummy, oacc, hlds);
        pass_fn<true, false, false>(h2prv, wg2h, wg2h, wout_lds, half, lane, tid, zoff,
                                    a2, dummy, oacc, hlds);
        float i2 = sigm(a2.x), f2 = sigm(a2.y), g2 = tanh_fast(a2.z), o2 = sigm(a2.w);
        c2 = fmaf(f2, c2, i2 * g2);
        cohstoref(&h2nxt[(size_t)u * Bdim + bcol], o2 * tanh_fast(c2));
        grid_barrier(arr, ++phase);
        if (douter) {                                          // O(511)
            float acc = 0.0f;
            const float* hb = h2nxt + bcol;
            const int k0 = w * 128;
            #pragma unroll 8
            for (int kk = 0; kk < 128; ++kk)
                acc = fmaf(cohloadf(&hb[(size_t)(k0 + kk) * Bdim]), wout_lds[k0 + kk], acc);
            partial[w][lane] = acc;
            __syncthreads();
            if (w == 0)
                out[(size_t)bcol * TT + 511] = partial[0][lane] + partial[1][lane]
                                             + partial[2][lane] + partial[3][lane] + bout0;
            __syncthreads();
        }
    }

    // ---- future phase t=512..543: 2 barriers/step, every block computes its own feedback
    for (int t = 512; t < TT; ++t) {
        const float* h1prv = ((t - 1) & 1) ? h1b1 : h1b0;      // h1(t-1)
        float*       h1nxt = (t & 1) ? h1b1 : h1b0;            // h1(t)
        const float* h2prv = (t & 1) ? h2b1 : h2b0;            // h2(t-1)
        float*       h2nxt = (t & 1) ? h2b0 : h2b1;            // h2(t)

        // F-a: O(t-1) locally (identical per bcol on every block), then C1(t)
        float oacc = 0.0f;
        pass_fn<false, false, true>(h2prv, wg1, wg1, wout_lds, half, lane, tid, zoff,
                                    dummy, dummy, oacc, hlds);
        float xv = oacc + bout0;
        if (douter && w == 0) out[(size_t)bcol * TT + (t - 1)] = xv;

        float4 a1 = { fmaf(wx1.x, xv, bias1.x), fmaf(wx1.y, xv, bias1.y),
                      fmaf(wx1.z, xv, bias1.z), fmaf(wx1.w, xv, bias1.w) };
        pass_fn<true, false, false>(h1prv, wg1, wg1, wout_lds, half, lane, tid, zoff,
                                    a1, dummy, oacc, hlds);
        float i1 = sigm(a1.x), f1 = sigm(a1.y), g1 = tanh_fast(a1.z), o1 = sigm(a1.w);
        c1 = fmaf(f1, c1, i1 * g1);
        cohstoref(&h1nxt[(size_t)u * Bdim + bcol], o1 * tanh_fast(c1));
        grid_barrier(arr, ++phase);

        // F-b: C2(t)
        float4 a2 = bias2;
        pass_fn<true, false, false>(h1nxt, wg2i, wg2i, wout_lds, half, lane, tid, zoff,
                                    a2, dummy, oacc, hlds);
        pass_fn<true, false, false>(h2prv, wg2h, wg2h, wout_lds, half, lane, tid, zoff,
                                    a2, dummy, oacc, hlds);
        float i2 = sigm(a2.x), f2 = sigm(a2.y), g2 = tanh_fast(a2.z), o2 = sigm(a2.w);
        c2 = fmaf(f2, c2, i2 * g2);
        cohstoref(&h2nxt[(size_t)u * Bdim + bcol], o2 * tanh_fast(c2));
        grid_barrier(arr, ++phase);
    }

    // ---- final O(543) (h2(543) in buf0, published at last barrier)
    if (douter) {
        float oacc = 0.0f;
        pass_fn<false, false, true>(h2b0, wg1, wg1, wout_lds, half, lane, tid, zoff,
                                    dummy, dummy, oacc, hlds);
        if (w == 0) out[(size_t)bcol * TT + (TT - 1)] = oacc + bout0;
    }
}

extern "C" void kernel_launch(void* const* d_in, const int* in_sizes, int n_in,
                              void* d_out, int out_size, void* d_ws, size_t ws_size,
                              hipStream_t stream) {
    const float* x     = (const float*)d_in[0];
    const float* W_ih1 = (const float*)d_in[1];
    const float* W_hh1 = (const float*)d_in[2];
    const float* b_ih1 = (const float*)d_in[3];
    const float* b_hh1 = (const float*)d_in[4];
    const float* W_ih2 = (const float*)d_in[5];
    const float* W_hh2 = (const float*)d_in[6];
    const float* b_ih2 = (const float*)d_in[7];
    const float* b_hh2 = (const float*)d_in[8];
    const float* W_out = (const float*)d_in[9];
    const float* b_out = (const float*)d_in[10];
    float* ws  = (float*)d_ws;
    float* out = (float*)d_out;

    hipLaunchKernelGGL(lstm_prep, dim3(1024), dim3(256), 0, stream,
                       x, W_ih1, W_hh1, b_ih1, b_hh1, W_ih2, W_hh2, b_ih2, b_hh2, ws);
    hipLaunchKernelGGL(lstm_main, dim3(NBLK), dim3(NTHR), 0, stream,
                       ws, W_out, b_out, out);
}

// Round 6
// 18533.257 us; speedup vs baseline: 1.6555x; 1.6555x over previous
//
#include <hip/hip_runtime.h>
#include <cstdint>

// ---- problem dims ----
#define Hdim 512
#define Bdim 128
#define Tdim 512
#define FUT  32
#define TT   (Tdim + FUT)   // 544
#define NB1  32             // layer-1 GEMM blocks (64 packed rows each)
#define NB2  64             // layer-2 GEMM blocks (32 packed rows each, K=1024)
#define NBO  2              // dedicated output blocks
#define NBLK (NB1 + NB2 + NBO)   // 98

typedef _Float16 f16;
typedef f16   half8 __attribute__((ext_vector_type(8)));
typedef float f32x4 __attribute__((ext_vector_type(4)));
typedef unsigned long long ull;

// ---- ws layout (float offsets) ----
// AW1: [128 mt][16 ks][2 spl][64 lane][8] halfs   (A-fragments of packed W_hh1)
// AW2: [128 mt][32 ks][2 spl][64 lane][8] halfs   (packed [W_ih2 | W_hh2], K=1024)
// H planes: [2 parity][2 spl(hi/lo)][128 b][512 u] halfs
#define AW1_OFF 0
#define AW2_OFF (AW1_OFF + 1048576)
#define B1P_OFF (AW2_OFF + 2097152)
#define B2P_OFF (B1P_OFF + 2048)
#define WX1_OFF (B2P_OFF + 2048)
#define XT_OFF  (WX1_OFF + 2048)      // [512 t][128 b] f32
#define H1P_OFF (XT_OFF + 65536)      // 4 planes x 32768 f = 131072
#define H2P_OFF (H1P_OFF + 131072)
#define ARR_OFF (H2P_OFF + 131072)    // [98] arrive flags
#define WS_FLOATS (ARR_OFF + 128)

__device__ __forceinline__ float sigm(float v) { return 1.0f / (1.0f + __expf(-v)); }
__device__ __forceinline__ float tanh_fast(float v) {
    v = fminf(fmaxf(v, -20.0f), 20.0f);
    float e = __expf(2.0f * v);
    return (e - 1.0f) / (e + 1.0f);
}

// ---- agent-scope relaxed accessors ----
__device__ __forceinline__ ull cohload64(const ull* p) {
    return __hip_atomic_load(p, __ATOMIC_RELAXED, __HIP_MEMORY_SCOPE_AGENT);
}
__device__ __forceinline__ void cohstoreh(unsigned short* p, f16 v) {
    unsigned short b = __builtin_bit_cast(unsigned short, v);
    __hip_atomic_store(p, b, __ATOMIC_RELAXED, __HIP_MEMORY_SCOPE_AGENT);
}

union HB { ull u[2]; half8 h; };
union U4 { ull u; f16 h[4]; };

// ---- flat fence-free grid barrier (R3-proven) ----
__device__ __forceinline__ void grid_barrier(unsigned* arr, unsigned phase) {
    __syncthreads();
    if (threadIdx.x == 0)
        __hip_atomic_store(&arr[blockIdx.x], phase, __ATOMIC_RELAXED, __HIP_MEMORY_SCOPE_AGENT);
    if (threadIdx.x < NBLK)
        while (__hip_atomic_load(&arr[threadIdx.x], __ATOMIC_RELAXED, __HIP_MEMORY_SCOPE_AGENT) < phase)
            __builtin_amdgcn_s_sleep(1);
    __syncthreads();
}

// ---------- prep ----------
__global__ void lstm_prep(const float* __restrict__ x,
                          const float* __restrict__ W_ih1, const float* __restrict__ W_hh1,
                          const float* __restrict__ b_ih1, const float* __restrict__ b_hh1,
                          const float* __restrict__ W_ih2, const float* __restrict__ W_hh2,
                          const float* __restrict__ b_ih2, const float* __restrict__ b_hh2,
                          float* __restrict__ ws) {
    int i = blockIdx.x * blockDim.x + threadIdx.x;
    f16* aw1 = (f16*)(ws + AW1_OFF);
    f16* aw2 = (f16*)(ws + AW2_OFF);

    if (i < 131072) {                         // AW1
        int mt = i >> 10, rest = i & 1023, ks = rest >> 6, lane = rest & 63;
        int m = mt * 16 + (lane & 15);
        int u = m >> 2, g = m & 3;
        int kbase = ks * 32 + (lane >> 4) * 8;
        size_t ohi = ((((size_t)mt * 16 + ks) * 2 + 0) * 64 + lane) * 8;
        size_t olo = ((((size_t)mt * 16 + ks) * 2 + 1) * 64 + lane) * 8;
        #pragma unroll
        for (int j = 0; j < 8; ++j) {
            float wv = W_hh1[(size_t)(g * Hdim + u) * Hdim + kbase + j];
            f16 hi = (f16)wv;
            f16 lo = (f16)(wv - (float)hi);
            aw1[ohi + j] = hi; aw1[olo + j] = lo;
        }
    }
    if (i >= 131072 && i < 393216) {          // AW2 (K=1024 concat)
        int i2 = i - 131072;
        int mt = i2 >> 11, rest = i2 & 2047, ks = rest >> 6, lane = rest & 63;
        int m = mt * 16 + (lane & 15);
        int u = m >> 2, g = m & 3;
        int kbase = ks * 32 + (lane >> 4) * 8;
        size_t ohi = ((((size_t)mt * 32 + ks) * 2 + 0) * 64 + lane) * 8;
        size_t olo = ((((size_t)mt * 32 + ks) * 2 + 1) * 64 + lane) * 8;
        #pragma unroll
        for (int j = 0; j < 8; ++j) {
            int k = kbase + j;
            float wv = (k < Hdim) ? W_ih2[(size_t)(g * Hdim + u) * Hdim + k]
                                  : W_hh2[(size_t)(g * Hdim + u) * Hdim + (k - Hdim)];
            f16 hi = (f16)wv;
            f16 lo = (f16)(wv - (float)hi);
            aw2[ohi + j] = hi; aw2[olo + j] = lo;
        }
    }
    if (i < Hdim) {
        float4 bb1 = { b_ih1[i] + b_hh1[i],               b_ih1[Hdim+i] + b_hh1[Hdim+i],
                       b_ih1[2*Hdim+i] + b_hh1[2*Hdim+i], b_ih1[3*Hdim+i] + b_hh1[3*Hdim+i] };
        float4 bb2 = { b_ih2[i] + b_hh2[i],               b_ih2[Hdim+i] + b_hh2[Hdim+i],
                       b_ih2[2*Hdim+i] + b_hh2[2*Hdim+i], b_ih2[3*Hdim+i] + b_hh2[3*Hdim+i] };
        float4 wx  = { W_ih1[i], W_ih1[Hdim+i], W_ih1[2*Hdim+i], W_ih1[3*Hdim+i] };
        ((float4*)(ws + B1P_OFF))[i] = bb1;
        ((float4*)(ws + B2P_OFF))[i] = bb2;
        ((float4*)(ws + WX1_OFF))[i] = wx;
    }
    if (i < Tdim * Bdim) {
        int t = i >> 7, b = i & 127;
        ws[XT_OFF + i] = x[b * Tdim + t];
    }
    if (i < 65536) {                           // zero all 4 planes of each h
        ((ull*)(ws + H1P_OFF))[i] = 0;
        ((ull*)(ws + H2P_OFF))[i] = 0;
    }
    if (i < 128) ((unsigned*)(ws + ARR_OFF))[i] = 0u;
}

// ---------- persistent MFMA main kernel ----------
__global__ __launch_bounds__(256) void lstm_main(float* ws,
                                                 const float* __restrict__ Wout,
                                                 const float* __restrict__ bout,
                                                 float* __restrict__ out) {
    const int tid  = threadIdx.x, bid = blockIdx.x;
    const int w    = tid >> 6;
    const int lane = tid & 63;
    const int quad = lane >> 4;
    const int col  = lane & 15;
    const bool is1  = (bid < NB1);
    const bool is2  = (bid >= NB1) && (bid < NB1 + NB2);
    const bool isout = (bid >= NB1 + NB2);

    __shared__ f16   awlds[65536];       // 128 KB weight A-fragments
    __shared__ float wout_lds[Hdim];
    __shared__ float psum[2][128];
    __shared__ float xflds[128];
    __shared__ float qpart[4][64];

    unsigned* arr = (unsigned*)(ws + ARR_OFF);
    const float* xT = ws + XT_OFF;
    const float bout0 = bout[0];

    auto h1p = [&](int par, int spl) { return (const ull*)(ws + H1P_OFF) + (size_t)(par*2 + spl) * 16384; };
    auto h2p = [&](int par, int spl) { return (const ull*)(ws + H2P_OFF) + (size_t)(par*2 + spl) * 16384; };
    auto h1s = [&](int par, int spl) { return (unsigned short*)(ws + H1P_OFF) + (size_t)(par*2 + spl) * 65536; };
    auto h2s = [&](int par, int spl) { return (unsigned short*)(ws + H2P_OFF) + (size_t)(par*2 + spl) * 65536; };

    // ---- one-time: weight slice -> LDS
    if (!isout) {
        half8* d = (half8*)awlds;
        const half8* s = (const half8*)(ws + (is1 ? AW1_OFF : AW2_OFF))
                       + (size_t)(is1 ? bid : bid - NB1) * 8192;
        for (int i = tid; i < 8192; i += 256) d[i] = s[i];
    }
    wout_lds[tid]       = Wout[tid];
    wout_lds[256 + tid] = Wout[256 + tid];
    __syncthreads();
    const half8* aw8 = (const half8*)awlds;

    int b_[2] = { w * 32 + col, w * 32 + 16 + col };
    int   u_[4];  float4 b1v[4], wxv[4];  float c1s[4][2];
    int   u2_[2]; float4 b2v[2];          float c2s[2][2];
    if (is1) {
        #pragma unroll
        for (int mt = 0; mt < 4; ++mt) {
            u_[mt]  = bid * 16 + mt * 4 + quad;
            b1v[mt] = ((const float4*)(ws + B1P_OFF))[u_[mt]];
            wxv[mt] = ((const float4*)(ws + WX1_OFF))[u_[mt]];
            c1s[mt][0] = c1s[mt][1] = 0.0f;
        }
    } else if (is2) {
        #pragma unroll
        for (int mt = 0; mt < 2; ++mt) {
            u2_[mt] = (bid - NB1) * 8 + mt * 4 + quad;
            b2v[mt] = ((const float4*)(ws + B2P_OFF))[u2_[mt]];
            c2s[mt][0] = c2s[mt][1] = 0.0f;
        }
    }

    // ---- layer-1: gates = Whi·hhi + Wlo·hhi + Whi·hlo + wx·x + b1
    auto gemm1 = [&](int spar, int dpar, float xv0, float xv1) {
        f32x4 acc[4][2] = {};
        const ull* ph[2] = { h1p(spar,0) + (size_t)b_[0]*128 + quad*2,
                             h1p(spar,0) + (size_t)b_[1]*128 + quad*2 };
        const ull* pl[2] = { h1p(spar,1) + (size_t)b_[0]*128 + quad*2,
                             h1p(spar,1) + (size_t)b_[1]*128 + quad*2 };
        HB bh[4][2], bl[4][2];
        #pragma unroll
        for (int ks = 0; ks < 4; ++ks)
            #pragma unroll
            for (int nt = 0; nt < 2; ++nt) {
                bh[ks][nt].u[0] = cohload64(ph[nt] + ks*8); bh[ks][nt].u[1] = cohload64(ph[nt] + ks*8 + 1);
                bl[ks][nt].u[0] = cohload64(pl[nt] + ks*8); bl[ks][nt].u[1] = cohload64(pl[nt] + ks*8 + 1);
            }
        #pragma unroll
        for (int ks = 0; ks < 16; ++ks) {
            half8 b0h = bh[ks&3][0].h, b1h = bh[ks&3][1].h;
            half8 b0l = bl[ks&3][0].h, b1l = bl[ks&3][1].h;
            if (ks < 12) {
                int kp = ks + 4;
                #pragma unroll
                for (int nt = 0; nt < 2; ++nt) {
                    bh[ks&3][nt].u[0] = cohload64(ph[nt] + kp*8); bh[ks&3][nt].u[1] = cohload64(ph[nt] + kp*8 + 1);
                    bl[ks&3][nt].u[0] = cohload64(pl[nt] + kp*8); bl[ks&3][nt].u[1] = cohload64(pl[nt] + kp*8 + 1);
                }
            }
            #pragma unroll
            for (int mt = 0; mt < 4; ++mt) {
                half8 ah = aw8[((mt*16 + ks)*2 + 0)*64 + lane];
                half8 al = aw8[((mt*16 + ks)*2 + 1)*64 + lane];
                acc[mt][0] = __builtin_amdgcn_mfma_f32_16x16x32_f16(ah, b0h, acc[mt][0], 0, 0, 0);
                acc[mt][0] = __builtin_amdgcn_mfma_f32_16x16x32_f16(al, b0h, acc[mt][0], 0, 0, 0);
                acc[mt][0] = __builtin_amdgcn_mfma_f32_16x16x32_f16(ah, b0l, acc[mt][0], 0, 0, 0);
                acc[mt][1] = __builtin_amdgcn_mfma_f32_16x16x32_f16(ah, b1h, acc[mt][1], 0, 0, 0);
                acc[mt][1] = __builtin_amdgcn_mfma_f32_16x16x32_f16(al, b1h, acc[mt][1], 0, 0, 0);
                acc[mt][1] = __builtin_amdgcn_mfma_f32_16x16x32_f16(ah, b1l, acc[mt][1], 0, 0, 0);
            }
        }
        float xv[2] = { xv0, xv1 };
        #pragma unroll
        for (int mt = 0; mt < 4; ++mt)
            #pragma unroll
            for (int nt = 0; nt < 2; ++nt) {
                f32x4 g = acc[mt][nt];
                float pi = g[0] + b1v[mt].x + wxv[mt].x * xv[nt];
                float pf = g[1] + b1v[mt].y + wxv[mt].y * xv[nt];
                float pg = g[2] + b1v[mt].z + wxv[mt].z * xv[nt];
                float po = g[3] + b1v[mt].w + wxv[mt].w * xv[nt];
                float c = fmaf(sigm(pf), c1s[mt][nt], sigm(pi) * tanh_fast(pg));
                c1s[mt][nt] = c;
                float hv = sigm(po) * tanh_fast(c);
                f16 hhi = (f16)hv;
                f16 hlo = (f16)(hv - (float)hhi);
                cohstoreh(h1s(dpar,0) + (size_t)b_[nt] * Hdim + u_[mt], hhi);
                cohstoreh(h1s(dpar,1) + (size_t)b_[nt] * Hdim + u_[mt], hlo);
            }
    };

    // ---- layer-2: gates = W2·[h1(t); h2(t-1)] (3-term) + b2
    auto gemm2 = [&](int t) {
        int cpar = t & 1, ppar = (t - 1) & 1;
        f32x4 acc[2][2] = {};
        const ull* pah[2] = { h1p(cpar,0) + (size_t)b_[0]*128 + quad*2,
                              h1p(cpar,0) + (size_t)b_[1]*128 + quad*2 };
        const ull* pal[2] = { h1p(cpar,1) + (size_t)b_[0]*128 + quad*2,
                              h1p(cpar,1) + (size_t)b_[1]*128 + quad*2 };
        const ull* pbh[2] = { h2p(ppar,0) + (size_t)b_[0]*128 + quad*2,
                              h2p(ppar,0) + (size_t)b_[1]*128 + quad*2 };
        const ull* pbl[2] = { h2p(ppar,1) + (size_t)b_[0]*128 + quad*2,
                              h2p(ppar,1) + (size_t)b_[1]*128 + quad*2 };
        HB bh[4][2], bl[4][2];
        #pragma unroll
        for (int ks = 0; ks < 4; ++ks)
            #pragma unroll
            for (int nt = 0; nt < 2; ++nt) {
                bh[ks][nt].u[0] = cohload64(pah[nt] + ks*8); bh[ks][nt].u[1] = cohload64(pah[nt] + ks*8 + 1);
                bl[ks][nt].u[0] = cohload64(pal[nt] + ks*8); bl[ks][nt].u[1] = cohload64(pal[nt] + ks*8 + 1);
            }
        #pragma unroll
        for (int ks = 0; ks < 32; ++ks) {
            half8 b0h = bh[ks&3][0].h, b1h = bh[ks&3][1].h;
            half8 b0l = bl[ks&3][0].h, b1l = bl[ks&3][1].h;
            if (ks < 28) {
                int kp = ks + 4;
                #pragma unroll
                for (int nt = 0; nt < 2; ++nt) {
                    const ull* qh = (kp < 16) ? (pah[nt] + kp*8) : (pbh[nt] + (kp-16)*8);
                    const ull* ql = (kp < 16) ? (pal[nt] + kp*8) : (pbl[nt] + (kp-16)*8);
                    bh[ks&3][nt].u[0] = cohload64(qh); bh[ks&3][nt].u[1] = cohload64(qh + 1);
                    bl[ks&3][nt].u[0] = cohload64(ql); bl[ks&3][nt].u[1] = cohload64(ql + 1);
                }
            }
            #pragma unroll
            for (int mt = 0; mt < 2; ++mt) {
                half8 ah = aw8[((mt*32 + ks)*2 + 0)*64 + lane];
                half8 al = aw8[((mt*32 + ks)*2 + 1)*64 + lane];
                acc[mt][0] = __builtin_amdgcn_mfma_f32_16x16x32_f16(ah, b0h, acc[mt][0], 0, 0, 0);
                acc[mt][0] = __builtin_amdgcn_mfma_f32_16x16x32_f16(al, b0h, acc[mt][0], 0, 0, 0);
                acc[mt][0] = __builtin_amdgcn_mfma_f32_16x16x32_f16(ah, b0l, acc[mt][0], 0, 0, 0);
                acc[mt][1] = __builtin_amdgcn_mfma_f32_16x16x32_f16(ah, b1h, acc[mt][1], 0, 0, 0);
                acc[mt][1] = __builtin_amdgcn_mfma_f32_16x16x32_f16(al, b1h, acc[mt][1], 0, 0, 0);
                acc[mt][1] = __builtin_amdgcn_mfma_f32_16x16x32_f16(ah, b1l, acc[mt][1], 0, 0, 0);
            }
        }
        #pragma unroll
        for (int mt = 0; mt < 2; ++mt)
            #pragma unroll
            for (int nt = 0; nt < 2; ++nt) {
                f32x4 g = acc[mt][nt];
                float pi = g[0] + b2v[mt].x;
                float pf = g[1] + b2v[mt].y;
                float pg = g[2] + b2v[mt].z;
                float po = g[3] + b2v[mt].w;
                float c = fmaf(sigm(pf), c2s[mt][nt], sigm(pi) * tanh_fast(pg));
                c2s[mt][nt] = c;
                float hv = sigm(po) * tanh_fast(c);
                f16 hhi = (f16)hv;
                f16 hlo = (f16)(hv - (float)hhi);
                cohstoreh(h2s(cpar,0) + (size_t)b_[nt] * Hdim + u2_[mt], hhi);
                cohstoreh(h2s(cpar,1) + (size_t)b_[nt] * Hdim + u2_[mt], hlo);
            }
    };

    // ---- quick out-dot O(t) (output blocks; hi+lo reconstruct) ----
    auto quickdot = [&](int t) {
        int b = (bid - NB1 - NB2) * 64 + lane;
        const ull* ph = h2p(t & 1, 0) + (size_t)b * 128 + w * 32;
        const ull* pl = h2p(t & 1, 1) + (size_t)b * 128 + w * 32;
        float a = 0.0f;
        #pragma unroll 8
        for (int kk = 0; kk < 32; ++kk) {
            U4 vh, vl; vh.u = cohload64(ph + kk); vl.u = cohload64(pl + kk);
            #pragma unroll
            for (int j = 0; j < 4; ++j)
                a = fmaf((float)vh.h[j] + (float)vl.h[j], wout_lds[w*128 + kk*4 + j], a);
        }
        qpart[w][lane] = a;
        __syncthreads();
        if (w == 0)
            out[(size_t)b * TT + t] = qpart[0][lane] + qpart[1][lane]
                                    + qpart[2][lane] + qpart[3][lane] + bout0;
        __syncthreads();
    };

    unsigned phase = 0;

    // ---- prologue: h1(0) from x(0) (h1(-1)=0) -> parity 0
    if (is1) {
        #pragma unroll
        for (int mt = 0; mt < 4; ++mt)
            #pragma unroll
            for (int nt = 0; nt < 2; ++nt) {
                float xv = xT[b_[nt]];
                float pi = b1v[mt].x + wxv[mt].x * xv;
                float pg = b1v[mt].z + wxv[mt].z * xv;
                float po = b1v[mt].w + wxv[mt].w * xv;
                float c = sigm(pi) * tanh_fast(pg);
                c1s[mt][nt] = c;
                float hv = sigm(po) * tanh_fast(c);
                f16 hhi = (f16)hv;
                f16 hlo = (f16)(hv - (float)hhi);
                cohstoreh(h1s(0,0) + (size_t)b_[nt] * Hdim + u_[mt], hhi);
                cohstoreh(h1s(0,1) + (size_t)b_[nt] * Hdim + u_[mt], hlo);
            }
    }
    grid_barrier(arr, ++phase);

    // ---- main phases t=0..511 ----
    for (int t = 0; t < Tdim; ++t) {
        if (is1) {
            if (t < Tdim - 1)
                gemm1(t & 1, (t + 1) & 1,
                      xT[(t + 1) * Bdim + b_[0]], xT[(t + 1) * Bdim + b_[1]]);
        } else if (is2) {
            gemm2(t);
        } else {
            if (t >= 1) quickdot(t - 1);       // h2(t-1) published last phase
        }
        grid_barrier(arr, ++phase);
    }

    // ---- future t=512..543 ----
    for (int t = Tdim; t < TT; ++t) {
        if (is1) {
            {   // cooperative O(t-1) as feedback
                int b = tid & 127, kh = tid >> 7;
                const ull* ph = h2p((t - 1) & 1, 0) + (size_t)b * 128 + kh * 64;
                const ull* pl = h2p((t - 1) & 1, 1) + (size_t)b * 128 + kh * 64;
                float a = 0.0f;
                #pragma unroll 8
                for (int kk = 0; kk < 64; ++kk) {
                    U4 vh, vl; vh.u = cohload64(ph + kk); vl.u = cohload64(pl + kk);
                    #pragma unroll
                    for (int j = 0; j < 4; ++j)
                        a = fmaf((float)vh.h[j] + (float)vl.h[j], wout_lds[kh*256 + kk*4 + j], a);
                }
                psum[kh][b] = a;
                __syncthreads();
                if (tid < 128) {
                    float xv = psum[0][tid] + psum[1][tid] + bout0;
                    xflds[tid] = xv;
                    if (bid == 0 && (t - 1) >= Tdim)
                        out[(size_t)tid * TT + (t - 1)] = xv;
                }
                __syncthreads();
            }
            gemm1((t - 1) & 1, t & 1, xflds[b_[0]], xflds[b_[1]]);
        } else if (isout) {
            if (t == Tdim) quickdot(Tdim - 1);   // O(511)
        }
        grid_barrier(arr, ++phase);
        if (is2) gemm2(t);
        grid_barrier(arr, ++phase);
    }

    // ---- final O(543)
    if (isout) quickdot(TT - 1);
}

extern "C" void kernel_launch(void* const* d_in, const int* in_sizes, int n_in,
                              void* d_out, int out_size, void* d_ws, size_t ws_size,
                              hipStream_t stream) {
    const float* x     = (const float*)d_in[0];
    const float* W_ih1 = (const float*)d_in[1];
    const float* W_hh1 = (const float*)d_in[2];
    const float* b_ih1 = (const float*)d_in[3];
    const float* b_hh1 = (const float*)d_in[4];
    const float* W_ih2 = (const float*)d_in[5];
    const float* W_hh2 = (const float*)d_in[6];
    const float* b_ih2 = (const float*)d_in[7];
    const float* b_hh2 = (const float*)d_in[8];
    const float* W_out = (const float*)d_in[9];
    const float* b_out = (const float*)d_in[10];
    float* ws  = (float*)d_ws;
    float* out = (float*)d_out;

    hipLaunchKernelGGL(lstm_prep, dim3(1536), dim3(256), 0, stream,
                       x, W_ih1, W_hh1, b_ih1, b_hh1, W_ih2, W_hh2, b_ih2, b_hh2, ws);
    hipLaunchKernelGGL(lstm_main, dim3(NBLK), dim3(256), 0, stream,
                       ws, W_out, b_out, out);
}

// Round 7
// 9209.230 us; speedup vs baseline: 3.3317x; 2.0125x over previous
//
#include <hip/hip_runtime.h>
#include <cstdint>

// ---- problem dims ----
#define Hdim 512
#define Bdim 128
#define Tdim 512
#define FUT  32
#define TT   (Tdim + FUT)   // 544
#define NB1  32             // layer-1 GEMM blocks (64 packed rows each)
#define NB2  64             // layer-2 GEMM blocks (32 packed rows each, K=1024)
#define NBO  2              // dedicated output blocks
#define NBLK (NB1 + NB2 + NBO)   // 98

typedef _Float16 f16;
typedef f16   half8 __attribute__((ext_vector_type(8)));
typedef float f32x4 __attribute__((ext_vector_type(4)));
typedef unsigned long long ull;

// ---- ws layout (float offsets) ----
// AW1: [128 mt][16 ks][2 spl][64 lane][8] halfs   (A-fragments of packed W_hh1)
// AW2: [128 mt][32 ks][2 spl][64 lane][8] halfs   (packed [W_ih2 | W_hh2], K=1024)
// H planes: fragment-interleaved f16: [par][spl][ (nt*16+ks)*64 + lane ][8]
//   element (b,u): nt=b>>4, ks=u>>5, lane=((u>>3)&3)*16+(b&15), j=u&7
#define AW1_OFF 0
#define AW2_OFF (AW1_OFF + 1048576)
#define B1P_OFF (AW2_OFF + 2097152)
#define B2P_OFF (B1P_OFF + 2048)
#define WX1_OFF (B2P_OFF + 2048)
#define XT_OFF  (WX1_OFF + 2048)      // [512 t][128 b] f32
#define H1P_OFF (XT_OFF + 65536)      // 4 planes x 65536 f16 = 131072 floats
#define H2P_OFF (H1P_OFF + 131072)
#define ARR_OFF (H2P_OFF + 131072)    // [0] = barrier counter
#define WS_FLOATS (ARR_OFF + 128)

__device__ __forceinline__ float sigm(float v) { return 1.0f / (1.0f + __expf(-v)); }
__device__ __forceinline__ float tanh_fast(float v) {
    v = fminf(fmaxf(v, -20.0f), 20.0f);
    float e = __expf(2.0f * v);
    return (e - 1.0f) / (e + 1.0f);
}

// agent-scope relaxed store (write-through to LLC) for cross-block h publication
__device__ __forceinline__ void cohstoreh(unsigned short* p, f16 v) {
    unsigned short b = __builtin_bit_cast(unsigned short, v);
    __hip_atomic_store(p, b, __ATOMIC_RELAXED, __HIP_MEMORY_SCOPE_AGENT);
}

// ---- counter barrier: thread0 atomic arrive + single-line poll + acquire fence ----
// Release: __syncthreads drains each wave's vmcnt (h write-through stores at LLC)
// before thread0's arrive RMW. Acquire: buffer_inv (L1+XCD-L2) so PLAIN h loads
// after the barrier refetch fresh lines from LLC; weights live in LDS, unaffected.
__device__ __forceinline__ void grid_barrier(unsigned* ctr, unsigned phase) {
    __syncthreads();
    if (threadIdx.x == 0) {
        __hip_atomic_fetch_add(ctr, 1u, __ATOMIC_RELAXED, __HIP_MEMORY_SCOPE_AGENT);
        while (__hip_atomic_load(ctr, __ATOMIC_RELAXED, __HIP_MEMORY_SCOPE_AGENT)
               < phase * (unsigned)NBLK)
            __builtin_amdgcn_s_sleep(2);
        __builtin_amdgcn_fence(__ATOMIC_ACQUIRE, "agent");
    }
    __syncthreads();
}

// ---------- prep ----------
__global__ void lstm_prep(const float* __restrict__ x,
                          const float* __restrict__ W_ih1, const float* __restrict__ W_hh1,
                          const float* __restrict__ b_ih1, const float* __restrict__ b_hh1,
                          const float* __restrict__ W_ih2, const float* __restrict__ W_hh2,
                          const float* __restrict__ b_ih2, const float* __restrict__ b_hh2,
                          float* __restrict__ ws) {
    int i = blockIdx.x * blockDim.x + threadIdx.x;
    f16* aw1 = (f16*)(ws + AW1_OFF);
    f16* aw2 = (f16*)(ws + AW2_OFF);

    if (i < 131072) {                         // AW1
        int mt = i >> 10, rest = i & 1023, ks = rest >> 6, lane = rest & 63;
        int m = mt * 16 + (lane & 15);
        int u = m >> 2, g = m & 3;
        int kbase = ks * 32 + (lane >> 4) * 8;
        size_t ohi = ((((size_t)mt * 16 + ks) * 2 + 0) * 64 + lane) * 8;
        size_t olo = ((((size_t)mt * 16 + ks) * 2 + 1) * 64 + lane) * 8;
        #pragma unroll
        for (int j = 0; j < 8; ++j) {
            float wv = W_hh1[(size_t)(g * Hdim + u) * Hdim + kbase + j];
            f16 hi = (f16)wv;
            f16 lo = (f16)(wv - (float)hi);
            aw1[ohi + j] = hi; aw1[olo + j] = lo;
        }
    }
    if (i >= 131072 && i < 393216) {          // AW2 (K=1024 concat)
        int i2 = i - 131072;
        int mt = i2 >> 11, rest = i2 & 2047, ks = rest >> 6, lane = rest & 63;
        int m = mt * 16 + (lane & 15);
        int u = m >> 2, g = m & 3;
        int kbase = ks * 32 + (lane >> 4) * 8;
        size_t ohi = ((((size_t)mt * 32 + ks) * 2 + 0) * 64 + lane) * 8;
        size_t olo = ((((size_t)mt * 32 + ks) * 2 + 1) * 64 + lane) * 8;
        #pragma unroll
        for (int j = 0; j < 8; ++j) {
            int k = kbase + j;
            float wv = (k < Hdim) ? W_ih2[(size_t)(g * Hdim + u) * Hdim + k]
                                  : W_hh2[(size_t)(g * Hdim + u) * Hdim + (k - Hdim)];
            f16 hi = (f16)wv;
            f16 lo = (f16)(wv - (float)hi);
            aw2[ohi + j] = hi; aw2[olo + j] = lo;
        }
    }
    if (i < Hdim) {
        float4 bb1 = { b_ih1[i] + b_hh1[i],               b_ih1[Hdim+i] + b_hh1[Hdim+i],
                       b_ih1[2*Hdim+i] + b_hh1[2*Hdim+i], b_ih1[3*Hdim+i] + b_hh1[3*Hdim+i] };
        float4 bb2 = { b_ih2[i] + b_hh2[i],               b_ih2[Hdim+i] + b_hh2[Hdim+i],
                       b_ih2[2*Hdim+i] + b_hh2[2*Hdim+i], b_ih2[3*Hdim+i] + b_hh2[3*Hdim+i] };
        float4 wx  = { W_ih1[i], W_ih1[Hdim+i], W_ih1[2*Hdim+i], W_ih1[3*Hdim+i] };
        ((float4*)(ws + B1P_OFF))[i] = bb1;
        ((float4*)(ws + B2P_OFF))[i] = bb2;
        ((float4*)(ws + WX1_OFF))[i] = wx;
    }
    if (i < Tdim * Bdim) {
        int t = i >> 7, b = i & 127;
        ws[XT_OFF + i] = x[b * Tdim + t];
    }
    if (i < 65536) {                           // zero all planes of h1,h2
        ((ull*)(ws + H1P_OFF))[i] = 0;
        ((ull*)(ws + H2P_OFF))[i] = 0;
    }
    if (i < 128) ((unsigned*)(ws + ARR_OFF))[i] = 0u;
}

// ---------- persistent MFMA main kernel ----------
__global__ __launch_bounds__(256) void lstm_main(float* ws,
                                                 const float* __restrict__ Wout,
                                                 const float* __restrict__ bout,
                                                 float* __restrict__ out) {
    const int tid  = threadIdx.x, bid = blockIdx.x;
    const int w    = tid >> 6;
    const int lane = tid & 63;
    const int quad = lane >> 4;
    const int col  = lane & 15;
    const bool is1  = (bid < NB1);
    const bool is2  = (bid >= NB1) && (bid < NB1 + NB2);
    const bool isout = (bid >= NB1 + NB2);

    __shared__ f16   awlds[65536];       // 128 KB weight A-fragments
    __shared__ float wout_lds[Hdim];
    __shared__ float psum[2][128];
    __shared__ float xflds[128];
    __shared__ float qpart[4][64];

    unsigned* ctr = (unsigned*)(ws + ARR_OFF);
    const float* xT = ws + XT_OFF;
    const float bout0 = bout[0];

    // fragment-plane accessors (PLAIN loads -> L2-cached; fence per phase)
    auto h1pl = [&](int par, int spl) {
        return (const half8*)((const unsigned short*)(ws + H1P_OFF) + (size_t)(par*2+spl) * 65536); };
    auto h2pl = [&](int par, int spl) {
        return (const half8*)((const unsigned short*)(ws + H2P_OFF) + (size_t)(par*2+spl) * 65536); };
    auto h1st = [&](int par, int spl) {
        return (unsigned short*)(ws + H1P_OFF) + (size_t)(par*2+spl) * 65536; };
    auto h2st = [&](int par, int spl) {
        return (unsigned short*)(ws + H2P_OFF) + (size_t)(par*2+spl) * 65536; };

    // ---- one-time: weight slice -> LDS
    if (!isout) {
        half8* d = (half8*)awlds;
        const half8* s = (const half8*)(ws + (is1 ? AW1_OFF : AW2_OFF))
                       + (size_t)(is1 ? bid : bid - NB1) * 8192;
        for (int i = tid; i < 8192; i += 256) d[i] = s[i];
    }
    wout_lds[tid]       = Wout[tid];
    wout_lds[256 + tid] = Wout[256 + tid];
    __syncthreads();
    const half8* aw8 = (const half8*)awlds;

    int b_[2] = { w * 32 + col, w * 32 + 16 + col };
    const int nt0 = 2 * w, nt1 = 2 * w + 1;
    int   u_[4];  float4 b1v[4], wxv[4];  float c1s[4][2];  int h1off[4][2];
    int   u2_[2]; float4 b2v[2];          float c2s[2][2];  int h2off[2][2];
    if (is1) {
        #pragma unroll
        for (int mt = 0; mt < 4; ++mt) {
            u_[mt]  = bid * 16 + mt * 4 + quad;
            b1v[mt] = ((const float4*)(ws + B1P_OFF))[u_[mt]];
            wxv[mt] = ((const float4*)(ws + WX1_OFF))[u_[mt]];
            c1s[mt][0] = c1s[mt][1] = 0.0f;
            #pragma unroll
            for (int nt = 0; nt < 2; ++nt) {
                int b = b_[nt], u = u_[mt];
                h1off[mt][nt] = ((((b>>4)*16 + (u>>5))*64) + (((u>>3)&3)*16 + (b&15)))*8 + (u&7);
            }
        }
    } else if (is2) {
        #pragma unroll
        for (int mt = 0; mt < 2; ++mt) {
            u2_[mt] = (bid - NB1) * 8 + mt * 4 + quad;
            b2v[mt] = ((const float4*)(ws + B2P_OFF))[u2_[mt]];
            c2s[mt][0] = c2s[mt][1] = 0.0f;
            #pragma unroll
            for (int nt = 0; nt < 2; ++nt) {
                int b = b_[nt], u = u2_[mt];
                h2off[mt][nt] = ((((b>>4)*16 + (u>>5))*64) + (((u>>3)&3)*16 + (b&15)))*8 + (u&7);
            }
        }
    }

    // ---- layer-1: gates = Whi·hhi + Wlo·hhi + Whi·hlo + wx·x + b1
    auto gemm1 = [&](int spar, int dpar, float xv0, float xv1) {
        f32x4 acc[4][2] = {};
        const half8* fh = h1pl(spar, 0);
        const half8* fl = h1pl(spar, 1);
        half8 bh[4][2], bl[4][2];
        #pragma unroll
        for (int ks = 0; ks < 4; ++ks) {
            bh[ks][0] = fh[(nt0*16+ks)*64 + lane]; bh[ks][1] = fh[(nt1*16+ks)*64 + lane];
            bl[ks][0] = fl[(nt0*16+ks)*64 + lane]; bl[ks][1] = fl[(nt1*16+ks)*64 + lane];
        }
        #pragma unroll
        for (int ks = 0; ks < 16; ++ks) {
            half8 b0h = bh[ks&3][0], b1h = bh[ks&3][1];
            half8 b0l = bl[ks&3][0], b1l = bl[ks&3][1];
            if (ks < 12) {
                int kp = ks + 4;
                bh[ks&3][0] = fh[(nt0*16+kp)*64 + lane]; bh[ks&3][1] = fh[(nt1*16+kp)*64 + lane];
                bl[ks&3][0] = fl[(nt0*16+kp)*64 + lane]; bl[ks&3][1] = fl[(nt1*16+kp)*64 + lane];
            }
            #pragma unroll
            for (int mt = 0; mt < 4; ++mt) {
                half8 ah = aw8[((mt*16 + ks)*2 + 0)*64 + lane];
                half8 al = aw8[((mt*16 + ks)*2 + 1)*64 + lane];
                acc[mt][0] = __builtin_amdgcn_mfma_f32_16x16x32_f16(ah, b0h, acc[mt][0], 0, 0, 0);
                acc[mt][0] = __builtin_amdgcn_mfma_f32_16x16x32_f16(al, b0h, acc[mt][0], 0, 0, 0);
                acc[mt][0] = __builtin_amdgcn_mfma_f32_16x16x32_f16(ah, b0l, acc[mt][0], 0, 0, 0);
                acc[mt][1] = __builtin_amdgcn_mfma_f32_16x16x32_f16(ah, b1h, acc[mt][1], 0, 0, 0);
                acc[mt][1] = __builtin_amdgcn_mfma_f32_16x16x32_f16(al, b1h, acc[mt][1], 0, 0, 0);
                acc[mt][1] = __builtin_amdgcn_mfma_f32_16x16x32_f16(ah, b1l, acc[mt][1], 0, 0, 0);
            }
        }
        float xv[2] = { xv0, xv1 };
        #pragma unroll
        for (int mt = 0; mt < 4; ++mt)
            #pragma unroll
            for (int nt = 0; nt < 2; ++nt) {
                f32x4 g = acc[mt][nt];
                float pi = g[0] + b1v[mt].x + wxv[mt].x * xv[nt];
                float pf = g[1] + b1v[mt].y + wxv[mt].y * xv[nt];
                float pg = g[2] + b1v[mt].z + wxv[mt].z * xv[nt];
                float po = g[3] + b1v[mt].w + wxv[mt].w * xv[nt];
                float c = fmaf(sigm(pf), c1s[mt][nt], sigm(pi) * tanh_fast(pg));
                c1s[mt][nt] = c;
                float hv = sigm(po) * tanh_fast(c);
                f16 hhi = (f16)hv;
                f16 hlo = (f16)(hv - (float)hhi);
                cohstoreh(h1st(dpar,0) + h1off[mt][nt], hhi);
                cohstoreh(h1st(dpar,1) + h1off[mt][nt], hlo);
            }
    };

    // ---- layer-2: gates = W2·[h1(t); h2(t-1)] (3-term) + b2
    auto gemm2 = [&](int t) {
        int cpar = t & 1, ppar = (t - 1) & 1;
        f32x4 acc[2][2] = {};
        const half8* fh = h1pl(cpar, 0);
        const half8* fl = h1pl(cpar, 1);
        const half8* gh = h2pl(ppar, 0);
        const half8* gl = h2pl(ppar, 1);
        half8 bh[4][2], bl[4][2];
        #pragma unroll
        for (int ks = 0; ks < 4; ++ks) {
            bh[ks][0] = fh[(nt0*16+ks)*64 + lane]; bh[ks][1] = fh[(nt1*16+ks)*64 + lane];
            bl[ks][0] = fl[(nt0*16+ks)*64 + lane]; bl[ks][1] = fl[(nt1*16+ks)*64 + lane];
        }
        #pragma unroll
        for (int ks = 0; ks < 32; ++ks) {
            half8 b0h = bh[ks&3][0], b1h = bh[ks&3][1];
            half8 b0l = bl[ks&3][0], b1l = bl[ks&3][1];
            if (ks < 28) {
                int kp = ks + 4;
                const half8* sh = (kp < 16) ? fh : gh;
                const half8* sl = (kp < 16) ? fl : gl;
                int kq = (kp < 16) ? kp : kp - 16;
                bh[ks&3][0] = sh[(nt0*16+kq)*64 + lane]; bh[ks&3][1] = sh[(nt1*16+kq)*64 + lane];
                bl[ks&3][0] = sl[(nt0*16+kq)*64 + lane]; bl[ks&3][1] = sl[(nt1*16+kq)*64 + lane];
            }
            #pragma unroll
            for (int mt = 0; mt < 2; ++mt) {
                half8 ah = aw8[((mt*32 + ks)*2 + 0)*64 + lane];
                half8 al = aw8[((mt*32 + ks)*2 + 1)*64 + lane];
                acc[mt][0] = __builtin_amdgcn_mfma_f32_16x16x32_f16(ah, b0h, acc[mt][0], 0, 0, 0);
                acc[mt][0] = __builtin_amdgcn_mfma_f32_16x16x32_f16(al, b0h, acc[mt][0], 0, 0, 0);
                acc[mt][0] = __builtin_amdgcn_mfma_f32_16x16x32_f16(ah, b0l, acc[mt][0], 0, 0, 0);
                acc[mt][1] = __builtin_amdgcn_mfma_f32_16x16x32_f16(ah, b1h, acc[mt][1], 0, 0, 0);
                acc[mt][1] = __builtin_amdgcn_mfma_f32_16x16x32_f16(al, b1h, acc[mt][1], 0, 0, 0);
                acc[mt][1] = __builtin_amdgcn_mfma_f32_16x16x32_f16(ah, b1l, acc[mt][1], 0, 0, 0);
            }
        }
        #pragma unroll
        for (int mt = 0; mt < 2; ++mt)
            #pragma unroll
            for (int nt = 0; nt < 2; ++nt) {
                f32x4 g = acc[mt][nt];
                float pi = g[0] + b2v[mt].x;
                float pf = g[1] + b2v[mt].y;
                float pg = g[2] + b2v[mt].z;
                float po = g[3] + b2v[mt].w;
                float c = fmaf(sigm(pf), c2s[mt][nt], sigm(pi) * tanh_fast(pg));
                c2s[mt][nt] = c;
                float hv = sigm(po) * tanh_fast(c);
                f16 hhi = (f16)hv;
                f16 hlo = (f16)(hv - (float)hhi);
                cohstoreh(h2st(cpar,0) + h2off[mt][nt], hhi);
                cohstoreh(h2st(cpar,1) + h2off[mt][nt], hlo);
            }
    };

    // ---- quick out-dot O(t) (out blocks; fragment-layout gather) ----
    auto quickdot = [&](int t) {
        int b = (bid - NB1 - NB2) * 64 + lane;
        int nt = b >> 4, nl = b & 15;
        const half8* ph = h2pl(t & 1, 0);
        const half8* pl = h2pl(t & 1, 1);
        float a = 0.0f;
        #pragma unroll
        for (int kk = 0; kk < 4; ++kk) {
            int ks = w * 4 + kk;
            #pragma unroll
            for (int qd = 0; qd < 4; ++qd) {
                half8 vh = ph[(nt*16+ks)*64 + qd*16 + nl];
                half8 vl = pl[(nt*16+ks)*64 + qd*16 + nl];
                int ub = ks*32 + qd*8;
                #pragma unroll
                for (int j = 0; j < 8; ++j)
                    a = fmaf((float)vh[j] + (float)vl[j], wout_lds[ub + j], a);
            }
        }
        qpart[w][lane] = a;
        __syncthreads();
        if (w == 0)
            out[(size_t)b * TT + t] = qpart[0][lane] + qpart[1][lane]
                                    + qpart[2][lane] + qpart[3][lane] + bout0;
        __syncthreads();
    };

    unsigned phase = 0;

    // ---- prologue: h1(0) from x(0) (h1(-1)=0) -> parity 0
    if (is1) {
        #pragma unroll
        for (int mt = 0; mt < 4; ++mt)
            #pragma unroll
            for (int nt = 0; nt < 2; ++nt) {
                float xv = xT[b_[nt]];
                float pi = b1v[mt].x + wxv[mt].x * xv;
                float pg = b1v[mt].z + wxv[mt].z * xv;
                float po = b1v[mt].w + wxv[mt].w * xv;
                float c = sigm(pi) * tanh_fast(pg);
                c1s[mt][nt] = c;
                float hv = sigm(po) * tanh_fast(c);
                f16 hhi = (f16)hv;
                f16 hlo = (f16)(hv - (float)hhi);
                cohstoreh(h1st(0,0) + h1off[mt][nt], hhi);
                cohstoreh(h1st(0,1) + h1off[mt][nt], hlo);
            }
    }
    grid_barrier(ctr, ++phase);

    // ---- main phases t=0..511 ----
    for (int t = 0; t < Tdim; ++t) {
        if (is1) {
            if (t < Tdim - 1)
                gemm1(t & 1, (t + 1) & 1,
                      xT[(t + 1) * Bdim + b_[0]], xT[(t + 1) * Bdim + b_[1]]);
        } else if (is2) {
            gemm2(t);
        } else {
            if (t >= 1) quickdot(t - 1);       // h2(t-1) published last phase
        }
        grid_barrier(ctr, ++phase);
    }

    // ---- future t=512..543 ----
    for (int t = Tdim; t < TT; ++t) {
        if (is1) {
            {   // cooperative O(t-1) as feedback (fragment gather over h2(t-1))
                int b = tid & 127, kh = tid >> 7;
                int nt = b >> 4, nl = b & 15;
                const half8* ph = h2pl((t - 1) & 1, 0);
                const half8* pl = h2pl((t - 1) & 1, 1);
                float a = 0.0f;
                #pragma unroll
                for (int kk = 0; kk < 8; ++kk) {
                    int ks = kh * 8 + kk;
                    #pragma unroll
                    for (int qd = 0; qd < 4; ++qd) {
                        half8 vh = ph[(nt*16+ks)*64 + qd*16 + nl];
                        half8 vl = pl[(nt*16+ks)*64 + qd*16 + nl];
                        int ub = ks*32 + qd*8;
                        #pragma unroll
                        for (int j = 0; j < 8; ++j)
                            a = fmaf((float)vh[j] + (float)vl[j], wout_lds[ub + j], a);
                    }
                }
                psum[kh][b] = a;
                __syncthreads();
                if (tid < 128) {
                    float xv = psum[0][tid] + psum[1][tid] + bout0;
                    xflds[tid] = xv;
                    if (bid == 0 && (t - 1) >= Tdim)
                        out[(size_t)tid * TT + (t - 1)] = xv;
                }
                __syncthreads();
            }
            gemm1((t - 1) & 1, t & 1, xflds[b_[0]], xflds[b_[1]]);
        } else if (isout) {
            if (t == Tdim) quickdot(Tdim - 1);   // O(511)
        }
        grid_barrier(ctr, ++phase);
        if (is2) gemm2(t);
        grid_barrier(ctr, ++phase);
    }

    // ---- final O(543)
    if (isout) quickdot(TT - 1);
}

extern "C" void kernel_launch(void* const* d_in, const int* in_sizes, int n_in,
                              void* d_out, int out_size, void* d_ws, size_t ws_size,
                              hipStream_t stream) {
    const float* x     = (const float*)d_in[0];
    const float* W_ih1 = (const float*)d_in[1];
    const float* W_hh1 = (const float*)d_in[2];
    const float* b_ih1 = (const float*)d_in[3];
    const float* b_hh1 = (const float*)d_in[4];
    const float* W_ih2 = (const float*)d_in[5];
    const float* W_hh2 = (const float*)d_in[6];
    const float* b_ih2 = (const float*)d_in[7];
    const float* b_hh2 = (const float*)d_in[8];
    const float* W_out = (const float*)d_in[9];
    const float* b_out = (const float*)d_in[10];
    float* ws  = (float*)d_ws;
    float* out = (float*)d_out;

    hipLaunchKernelGGL(lstm_prep, dim3(1536), dim3(256), 0, stream,
                       x, W_ih1, W_hh1, b_ih1, b_hh1, W_ih2, W_hh2, b_ih2, b_hh2, ws);
    hipLaunchKernelGGL(lstm_main, dim3(NBLK), dim3(256), 0, stream,
                       ws, W_out, b_out, out);
}

// Round 8
// 8989.987 us; speedup vs baseline: 3.4129x; 1.0244x over previous
//
#include <hip/hip_runtime.h>
#include <cstdint>

// ---- problem dims ----
#define Hdim 512
#define Bdim 128
#define Tdim 512
#define FUT  32
#define TT   (Tdim + FUT)   // 544
#define NB1  32             // layer-1 GEMM blocks (16 units each)
#define NB2  64             // layer-2 GEMM blocks (8 units each, K=1024)
#define NBO  2              // trailing output blocks
#define NBLK (NB1 + NB2 + NBO)   // 98

typedef _Float16 f16;
typedef f16   half8 __attribute__((ext_vector_type(8)));
typedef float f32x4 __attribute__((ext_vector_type(4)));
typedef unsigned long long ull;

// ---- ws layout (float offsets) ----
// AW1: [128 mt][16 ks][2 spl][64 lane][8] halfs   (A-fragments of packed W_hh1)
// AW2: [128 mt][32 ks][2 spl][64 lane][8] halfs   (packed [W_ih2 | W_hh2], K=1024)
// H planes: fragment-interleaved f16, 4-deep ring: [par 0..3][spl][(nt*16+ks)*64+lane][8]
//   element (b,u): nt=b>>4, ks=u>>5, lane=((u>>3)&3)*16+(b&15), j=u&7
#define AW1_OFF 0
#define AW2_OFF (AW1_OFF + 1048576)
#define B1P_OFF (AW2_OFF + 2097152)
#define B2P_OFF (B1P_OFF + 2048)
#define WX1_OFF (B2P_OFF + 2048)
#define XT_OFF  (WX1_OFF + 2048)      // [512 t][128 b] f32
#define H1P_OFF (XT_OFF + 65536)      // 4 par x 2 spl x 65536 f16 = 262144 floats
#define H2P_OFF (H1P_OFF + 262144)
#define ARR_OFF (H2P_OFF + 262144)    // ctr1@0, ctr2@32, ctro@64 (separate lines)
#define WS_FLOATS (ARR_OFF + 128)

__device__ __forceinline__ float sigm(float v) { return 1.0f / (1.0f + __expf(-v)); }
__device__ __forceinline__ float tanh_fast(float v) {
    v = fminf(fmaxf(v, -20.0f), 20.0f);
    float e = __expf(2.0f * v);
    return (e - 1.0f) / (e + 1.0f);
}

// agent-scope relaxed store (write-through at LLC) for cross-block h publication
__device__ __forceinline__ void cohstoreh(unsigned short* p, f16 v) {
    unsigned short b = __builtin_bit_cast(unsigned short, v);
    __hip_atomic_store(p, b, __ATOMIC_RELAXED, __HIP_MEMORY_SCOPE_AGENT);
}
__device__ __forceinline__ void wait_ge(unsigned* p, unsigned target) {
    while (__hip_atomic_load(p, __ATOMIC_RELAXED, __HIP_MEMORY_SCOPE_AGENT) < target)
        __builtin_amdgcn_s_sleep(1);
}
__device__ __forceinline__ void arrive(unsigned* p) {
    __hip_atomic_fetch_add(p, 1u, __ATOMIC_RELAXED, __HIP_MEMORY_SCOPE_AGENT);
}

// ---------- prep ----------
__global__ void lstm_prep(const float* __restrict__ x,
                          const float* __restrict__ W_ih1, const float* __restrict__ W_hh1,
                          const float* __restrict__ b_ih1, const float* __restrict__ b_hh1,
                          const float* __restrict__ W_ih2, const float* __restrict__ W_hh2,
                          const float* __restrict__ b_ih2, const float* __restrict__ b_hh2,
                          float* __restrict__ ws) {
    int i = blockIdx.x * blockDim.x + threadIdx.x;
    f16* aw1 = (f16*)(ws + AW1_OFF);
    f16* aw2 = (f16*)(ws + AW2_OFF);

    if (i < 131072) {                         // AW1
        int mt = i >> 10, rest = i & 1023, ks = rest >> 6, lane = rest & 63;
        int m = mt * 16 + (lane & 15);
        int u = m >> 2, g = m & 3;
        int kbase = ks * 32 + (lane >> 4) * 8;
        size_t ohi = ((((size_t)mt * 16 + ks) * 2 + 0) * 64 + lane) * 8;
        size_t olo = ((((size_t)mt * 16 + ks) * 2 + 1) * 64 + lane) * 8;
        #pragma unroll
        for (int j = 0; j < 8; ++j) {
            float wv = W_hh1[(size_t)(g * Hdim + u) * Hdim + kbase + j];
            f16 hi = (f16)wv;
            f16 lo = (f16)(wv - (float)hi);
            aw1[ohi + j] = hi; aw1[olo + j] = lo;
        }
    }
    if (i >= 131072 && i < 393216) {          // AW2 (K=1024 concat)
        int i2 = i - 131072;
        int mt = i2 >> 11, rest = i2 & 2047, ks = rest >> 6, lane = rest & 63;
        int m = mt * 16 + (lane & 15);
        int u = m >> 2, g = m & 3;
        int kbase = ks * 32 + (lane >> 4) * 8;
        size_t ohi = ((((size_t)mt * 32 + ks) * 2 + 0) * 64 + lane) * 8;
        size_t olo = ((((size_t)mt * 32 + ks) * 2 + 1) * 64 + lane) * 8;
        #pragma unroll
        for (int j = 0; j < 8; ++j) {
            int k = kbase + j;
            float wv = (k < Hdim) ? W_ih2[(size_t)(g * Hdim + u) * Hdim + k]
                                  : W_hh2[(size_t)(g * Hdim + u) * Hdim + (k - Hdim)];
            f16 hi = (f16)wv;
            f16 lo = (f16)(wv - (float)hi);
            aw2[ohi + j] = hi; aw2[olo + j] = lo;
        }
    }
    if (i < Hdim) {
        float4 bb1 = { b_ih1[i] + b_hh1[i],               b_ih1[Hdim+i] + b_hh1[Hdim+i],
                       b_ih1[2*Hdim+i] + b_hh1[2*Hdim+i], b_ih1[3*Hdim+i] + b_hh1[3*Hdim+i] };
        float4 bb2 = { b_ih2[i] + b_hh2[i],               b_ih2[Hdim+i] + b_hh2[Hdim+i],
                       b_ih2[2*Hdim+i] + b_hh2[2*Hdim+i], b_ih2[3*Hdim+i] + b_hh2[3*Hdim+i] };
        float4 wx  = { W_ih1[i], W_ih1[Hdim+i], W_ih1[2*Hdim+i], W_ih1[3*Hdim+i] };
        ((float4*)(ws + B1P_OFF))[i] = bb1;
        ((float4*)(ws + B2P_OFF))[i] = bb2;
        ((float4*)(ws + WX1_OFF))[i] = wx;
    }
    if (i < Tdim * Bdim) {
        int t = i >> 7, b = i & 127;
        ws[XT_OFF + i] = x[b * Tdim + t];
    }
    if (i < 131072) {                          // zero all 4 parities x 2 spl of h1,h2
        ((ull*)(ws + H1P_OFF))[i] = 0;
        ((ull*)(ws + H2P_OFF))[i] = 0;
    }
    if (i < 128) ((unsigned*)(ws + ARR_OFF))[i] = 0u;
}

// ---------- persistent MFMA main kernel (async 3-group pipeline) ----------
__global__ __launch_bounds__(256, 1) void lstm_main(float* ws,
                                                    const float* __restrict__ Wout,
                                                    const float* __restrict__ bout,
                                                    float* __restrict__ out) {
    const int tid  = threadIdx.x, bid = blockIdx.x;
    const int w    = tid >> 6;
    const int lane = tid & 63;
    const int quad = lane >> 4;
    const int col  = lane & 15;
    const bool is1  = (bid < NB1);
    const bool is2  = (bid >= NB1) && (bid < NB1 + NB2);
    const bool isout = (bid >= NB1 + NB2);

    __shared__ f16   awlds[65536];       // 128 KB weight A-fragments
    __shared__ float wout_lds[Hdim];
    __shared__ float psum[2][128];
    __shared__ float xflds[128];
    __shared__ float qpart[4][64];

    unsigned* ctr1 = (unsigned*)(ws + ARR_OFF);
    unsigned* ctr2 = (unsigned*)(ws + ARR_OFF) + 32;
    unsigned* ctro = (unsigned*)(ws + ARR_OFF) + 64;
    const float* xT = ws + XT_OFF;
    const float bout0 = bout[0];

    // fragment-plane accessors (PLAIN loads -> L2-cached; acquire-inv per step)
    auto h1pl = [&](int par, int spl) {
        return (const half8*)((const unsigned short*)(ws + H1P_OFF) + (size_t)(par*2+spl) * 65536); };
    auto h2pl = [&](int par, int spl) {
        return (const half8*)((const unsigned short*)(ws + H2P_OFF) + (size_t)(par*2+spl) * 65536); };
    auto h1st = [&](int par, int spl) {
        return (unsigned short*)(ws + H1P_OFF) + (size_t)(par*2+spl) * 65536; };
    auto h2st = [&](int par, int spl) {
        return (unsigned short*)(ws + H2P_OFF) + (size_t)(par*2+spl) * 65536; };

    // ---- one-time: weight slice -> LDS
    if (!isout) {
        half8* d = (half8*)awlds;
        const half8* s = (const half8*)(ws + (is1 ? AW1_OFF : AW2_OFF))
                       + (size_t)(is1 ? bid : bid - NB1) * 8192;
        for (int i = tid; i < 8192; i += 256) d[i] = s[i];
    }
    wout_lds[tid]       = Wout[tid];
    wout_lds[256 + tid] = Wout[256 + tid];
    __syncthreads();
    const half8* aw8 = (const half8*)awlds;

    int b_[2] = { w * 32 + col, w * 32 + 16 + col };
    const int nt0 = 2 * w, nt1 = 2 * w + 1;
    int   u_[4];  float4 b1v[4], wxv[4];  float c1s[4][2];  int h1off[4][2];
    int   u2_[2]; float4 b2v[2];          float c2s[2][2];  int h2off[2][2];
    if (is1) {
        #pragma unroll
        for (int mt = 0; mt < 4; ++mt) {
            u_[mt]  = bid * 16 + mt * 4 + quad;
            b1v[mt] = ((const float4*)(ws + B1P_OFF))[u_[mt]];
            wxv[mt] = ((const float4*)(ws + WX1_OFF))[u_[mt]];
            c1s[mt][0] = c1s[mt][1] = 0.0f;
            #pragma unroll
            for (int nt = 0; nt < 2; ++nt) {
                int b = b_[nt], u = u_[mt];
                h1off[mt][nt] = ((((b>>4)*16 + (u>>5))*64) + (((u>>3)&3)*16 + (b&15)))*8 + (u&7);
            }
        }
    } else if (is2) {
        #pragma unroll
        for (int mt = 0; mt < 2; ++mt) {
            u2_[mt] = (bid - NB1) * 8 + mt * 4 + quad;
            b2v[mt] = ((const float4*)(ws + B2P_OFF))[u2_[mt]];
            c2s[mt][0] = c2s[mt][1] = 0.0f;
            #pragma unroll
            for (int nt = 0; nt < 2; ++nt) {
                int b = b_[nt], u = u2_[mt];
                h2off[mt][nt] = ((((b>>4)*16 + (u>>5))*64) + (((u>>3)&3)*16 + (b&15)))*8 + (u&7);
            }
        }
    }

    // ---- layer-1: gates = Whi·hhi + Wlo·hhi + Whi·hlo + wx·x + b1 (8-deep ring)
    auto gemm1 = [&](int spar, int dpar, float xv0, float xv1) {
        f32x4 acc[4][2] = {};
        const half8* fh = h1pl(spar, 0);
        const half8* fl = h1pl(spar, 1);
        half8 bh[8][2], bl[8][2];
        #pragma unroll
        for (int ks = 0; ks < 8; ++ks) {
            bh[ks][0] = fh[(nt0*16+ks)*64 + lane]; bh[ks][1] = fh[(nt1*16+ks)*64 + lane];
            bl[ks][0] = fl[(nt0*16+ks)*64 + lane]; bl[ks][1] = fl[(nt1*16+ks)*64 + lane];
        }
        #pragma unroll
        for (int ks = 0; ks < 16; ++ks) {
            half8 b0h = bh[ks&7][0], b1h = bh[ks&7][1];
            half8 b0l = bl[ks&7][0], b1l = bl[ks&7][1];
            if (ks < 8) {
                int kp = ks + 8;
                bh[ks&7][0] = fh[(nt0*16+kp)*64 + lane]; bh[ks&7][1] = fh[(nt1*16+kp)*64 + lane];
                bl[ks&7][0] = fl[(nt0*16+kp)*64 + lane]; bl[ks&7][1] = fl[(nt1*16+kp)*64 + lane];
            }
            #pragma unroll
            for (int mt = 0; mt < 4; ++mt) {
                half8 ah = aw8[((mt*16 + ks)*2 + 0)*64 + lane];
                half8 al = aw8[((mt*16 + ks)*2 + 1)*64 + lane];
                acc[mt][0] = __builtin_amdgcn_mfma_f32_16x16x32_f16(ah, b0h, acc[mt][0], 0, 0, 0);
                acc[mt][0] = __builtin_amdgcn_mfma_f32_16x16x32_f16(al, b0h, acc[mt][0], 0, 0, 0);
                acc[mt][0] = __builtin_amdgcn_mfma_f32_16x16x32_f16(ah, b0l, acc[mt][0], 0, 0, 0);
                acc[mt][1] = __builtin_amdgcn_mfma_f32_16x16x32_f16(ah, b1h, acc[mt][1], 0, 0, 0);
                acc[mt][1] = __builtin_amdgcn_mfma_f32_16x16x32_f16(al, b1h, acc[mt][1], 0, 0, 0);
                acc[mt][1] = __builtin_amdgcn_mfma_f32_16x16x32_f16(ah, b1l, acc[mt][1], 0, 0, 0);
            }
        }
        float xv[2] = { xv0, xv1 };
        #pragma unroll
        for (int mt = 0; mt < 4; ++mt)
            #pragma unroll
            for (int nt = 0; nt < 2; ++nt) {
                f32x4 g = acc[mt][nt];
                float pi = g[0] + b1v[mt].x + wxv[mt].x * xv[nt];
                float pf = g[1] + b1v[mt].y + wxv[mt].y * xv[nt];
                float pg = g[2] + b1v[mt].z + wxv[mt].z * xv[nt];
                float po = g[3] + b1v[mt].w + wxv[mt].w * xv[nt];
                float c = fmaf(sigm(pf), c1s[mt][nt], sigm(pi) * tanh_fast(pg));
                c1s[mt][nt] = c;
                float hv = sigm(po) * tanh_fast(c);
                f16 hhi = (f16)hv;
                f16 hlo = (f16)(hv - (float)hhi);
                cohstoreh(h1st(dpar,0) + h1off[mt][nt], hhi);
                cohstoreh(h1st(dpar,1) + h1off[mt][nt], hlo);
            }
    };

    // ---- layer-2: gates = W2·[h1(s); h2(s-1)] (3-term, 8-deep ring)
    auto gemm2 = [&](int s) {
        int cpar = s & 3, ppar = (s - 1) & 3;
        f32x4 acc[2][2] = {};
        const half8* fh = h1pl(cpar, 0);
        const half8* fl = h1pl(cpar, 1);
        const half8* gh = h2pl(ppar, 0);
        const half8* gl = h2pl(ppar, 1);
        half8 bh[8][2], bl[8][2];
        #pragma unroll
        for (int ks = 0; ks < 8; ++ks) {
            bh[ks][0] = fh[(nt0*16+ks)*64 + lane]; bh[ks][1] = fh[(nt1*16+ks)*64 + lane];
            bl[ks][0] = fl[(nt0*16+ks)*64 + lane]; bl[ks][1] = fl[(nt1*16+ks)*64 + lane];
        }
        #pragma unroll
        for (int ks = 0; ks < 32; ++ks) {
            half8 b0h = bh[ks&7][0], b1h = bh[ks&7][1];
            half8 b0l = bl[ks&7][0], b1l = bl[ks&7][1];
            if (ks < 24) {
                int kp = ks + 8;
                const half8* sh = (kp < 16) ? fh : gh;
                const half8* sl = (kp < 16) ? fl : gl;
                int kq = (kp < 16) ? kp : kp - 16;
                bh[ks&7][0] = sh[(nt0*16+kq)*64 + lane]; bh[ks&7][1] = sh[(nt1*16+kq)*64 + lane];
                bl[ks&7][0] = sl[(nt0*16+kq)*64 + lane]; bl[ks&7][1] = sl[(nt1*16+kq)*64 + lane];
            }
            #pragma unroll
            for (int mt = 0; mt < 2; ++mt) {
                half8 ah = aw8[((mt*32 + ks)*2 + 0)*64 + lane];
                half8 al = aw8[((mt*32 + ks)*2 + 1)*64 + lane];
                acc[mt][0] = __builtin_amdgcn_mfma_f32_16x16x32_f16(ah, b0h, acc[mt][0], 0, 0, 0);
                acc[mt][0] = __builtin_amdgcn_mfma_f32_16x16x32_f16(al, b0h, acc[mt][0], 0, 0, 0);
                acc[mt][0] = __builtin_amdgcn_mfma_f32_16x16x32_f16(ah, b0l, acc[mt][0], 0, 0, 0);
                acc[mt][1] = __builtin_amdgcn_mfma_f32_16x16x32_f16(ah, b1h, acc[mt][1], 0, 0, 0);
                acc[mt][1] = __builtin_amdgcn_mfma_f32_16x16x32_f16(al, b1h, acc[mt][1], 0, 0, 0);
                acc[mt][1] = __builtin_amdgcn_mfma_f32_16x16x32_f16(ah, b1l, acc[mt][1], 0, 0, 0);
            }
        }
        #pragma unroll
        for (int mt = 0; mt < 2; ++mt)
            #pragma unroll
            for (int nt = 0; nt < 2; ++nt) {
                f32x4 g = acc[mt][nt];
                float pi = g[0] + b2v[mt].x;
                float pf = g[1] + b2v[mt].y;
                float pg = g[2] + b2v[mt].z;
                float po = g[3] + b2v[mt].w;
                float c = fmaf(sigm(pf), c2s[mt][nt], sigm(pi) * tanh_fast(pg));
                c2s[mt][nt] = c;
                float hv = sigm(po) * tanh_fast(c);
                f16 hhi = (f16)hv;
                f16 hlo = (f16)(hv - (float)hhi);
                cohstoreh(h2st(cpar,0) + h2off[mt][nt], hhi);
                cohstoreh(h2st(cpar,1) + h2off[mt][nt], hlo);
            }
    };

    // ================= GROUP 1: layer-1 recurrence =================
    if (is1) {
        // prologue: h1(0) from x(0) (h1(-1)=0) -> parity 0
        #pragma unroll
        for (int mt = 0; mt < 4; ++mt)
            #pragma unroll
            for (int nt = 0; nt < 2; ++nt) {
                float xv = xT[b_[nt]];
                float pi = b1v[mt].x + wxv[mt].x * xv;
                float pg = b1v[mt].z + wxv[mt].z * xv;
                float po = b1v[mt].w + wxv[mt].w * xv;
                float c = sigm(pi) * tanh_fast(pg);
                c1s[mt][nt] = c;
                float hv = sigm(po) * tanh_fast(c);
                f16 hhi = (f16)hv;
                f16 hlo = (f16)(hv - (float)hhi);
                cohstoreh(h1st(0,0) + h1off[mt][nt], hhi);
                cohstoreh(h1st(0,1) + h1off[mt][nt], hlo);
            }
        __syncthreads();
        if (tid == 0) arrive(ctr1);

        // main: step t publishes h1(t+1); throttled by G2 (ring depth 4)
        for (int t = 0; t <= Tdim - 2; ++t) {
            if (tid == 0) {
                wait_ge(ctr1, 32u * (unsigned)(t + 1));       // own group: h1(t) complete
                if (t >= 3) wait_ge(ctr2, 64u * (unsigned)(t - 2));  // ring-overwrite guard
                __builtin_amdgcn_fence(__ATOMIC_ACQUIRE, "agent");
            }
            __syncthreads();
            gemm1(t & 3, (t + 1) & 3,
                  xT[(t + 1) * Bdim + b_[0]], xT[(t + 1) * Bdim + b_[1]]);
            __syncthreads();
            if (tid == 0) arrive(ctr1);
        }

        // future: step t computes feedback O(t-1) then publishes h1(t)
        for (int t = Tdim; t < TT; ++t) {
            if (tid == 0) {
                wait_ge(ctr1, 32u * (unsigned)t);             // own: h1(t-1) complete
                wait_ge(ctr2, 64u * (unsigned)t);             // h2(t-1) complete
                __builtin_amdgcn_fence(__ATOMIC_ACQUIRE, "agent");
            }
            __syncthreads();
            {   // cooperative O(t-1) from h2(t-1) fragments
                int b = tid & 127, kh = tid >> 7;
                int nt = b >> 4, nl = b & 15;
                const half8* ph = h2pl((t - 1) & 3, 0);
                const half8* pl = h2pl((t - 1) & 3, 1);
                float a = 0.0f;
                #pragma unroll
                for (int kk = 0; kk < 8; ++kk) {
                    int ks = kh * 8 + kk;
                    #pragma unroll
                    for (int qd = 0; qd < 4; ++qd) {
                        half8 vh = ph[(nt*16+ks)*64 + qd*16 + nl];
                        half8 vl = pl[(nt*16+ks)*64 + qd*16 + nl];
                        int ub = ks*32 + qd*8;
                        #pragma unroll
                        for (int j = 0; j < 8; ++j)
                            a = fmaf((float)vh[j] + (float)vl[j], wout_lds[ub + j], a);
                    }
                }
                psum[kh][b] = a;
                __syncthreads();
                if (tid < 128) xflds[tid] = psum[0][tid] + psum[1][tid] + bout0;
                __syncthreads();
            }
            gemm1((t - 1) & 3, t & 3, xflds[b_[0]], xflds[b_[1]]);
            __syncthreads();
            if (tid == 0) arrive(ctr1);
        }
    }
    // ================= GROUP 2: layer-2 (uniform loop) =================
    else if (is2) {
        for (int s = 0; s < TT; ++s) {
            if (tid == 0) {
                wait_ge(ctr2, 64u * (unsigned)s);             // own group: h2(s-1) complete
                wait_ge(ctr1, 32u * (unsigned)(s + 1));       // h1(s) ready
                if (s >= 4) wait_ge(ctro, 2u * (unsigned)(s - 3)); // out ring guard
                __builtin_amdgcn_fence(__ATOMIC_ACQUIRE, "agent");
            }
            __syncthreads();
            gemm2(s);
            __syncthreads();
            if (tid == 0) arrive(ctr2);
        }
    }
    // ================= OUT blocks: trail G2 =================
    else {
        int b = (bid - NB1 - NB2) * 64 + lane;
        int nt = b >> 4, nl = b & 15;
        for (int s = 0; s < TT; ++s) {
            if (tid == 0) {
                wait_ge(ctr2, 64u * (unsigned)(s + 1));       // h2(s) ready
                __builtin_amdgcn_fence(__ATOMIC_ACQUIRE, "agent");
            }
            __syncthreads();
            const half8* ph = h2pl(s & 3, 0);
            const half8* pl = h2pl(s & 3, 1);
            float a = 0.0f;
            #pragma unroll
            for (int kk = 0; kk < 4; ++kk) {
                int ks = w * 4 + kk;
                #pragma unroll
                for (int qd = 0; qd < 4; ++qd) {
                    half8 vh = ph[(nt*16+ks)*64 + qd*16 + nl];
                    half8 vl = pl[(nt*16+ks)*64 + qd*16 + nl];
                    int ub = ks*32 + qd*8;
                    #pragma unroll
                    for (int j = 0; j < 8; ++j)
                        a = fmaf((float)vh[j] + (float)vl[j], wout_lds[ub + j], a);
                }
            }
            qpart[w][lane] = a;
            __syncthreads();
            if (w == 0)
                out[(size_t)b * TT + s] = qpart[0][lane] + qpart[1][lane]
                                        + qpart[2][lane] + qpart[3][lane] + bout0;
            __syncthreads();
            if (tid == 0) arrive(ctro);
        }
    }
}

extern "C" void kernel_launch(void* const* d_in, const int* in_sizes, int n_in,
                              void* d_out, int out_size, void* d_ws, size_t ws_size,
                              hipStream_t stream) {
    const float* x     = (const float*)d_in[0];
    const float* W_ih1 = (const float*)d_in[1];
    const float* W_hh1 = (const float*)d_in[2];
    const float* b_ih1 = (const float*)d_in[3];
    const float* b_hh1 = (const float*)d_in[4];
    const float* W_ih2 = (const float*)d_in[5];
    const float* W_hh2 = (const float*)d_in[6];
    const float* b_ih2 = (const float*)d_in[7];
    const float* b_hh2 = (const float*)d_in[8];
    const float* W_out = (const float*)d_in[9];
    const float* b_out = (const float*)d_in[10];
    float* ws  = (float*)d_ws;
    float* out = (float*)d_out;

    hipLaunchKernelGGL(lstm_prep, dim3(1536), dim3(256), 0, stream,
                       x, W_ih1, W_hh1, b_ih1, b_hh1, W_ih2, W_hh2, b_ih2, b_hh2, ws);
    hipLaunchKernelGGL(lstm_main, dim3(NBLK), dim3(256), 0, stream,
                       ws, W_out, b_out, out);
}

// Round 9
// 8472.534 us; speedup vs baseline: 3.6214x; 1.0611x over previous
//
#include <hip/hip_runtime.h>
#include <cstdint>

// ---- problem dims ----
#define Hdim 512
#define Bdim 128
#define Tdim 512
#define FUT  32
#define TT   (Tdim + FUT)   // 544
#define NB1  32             // layer-1 GEMM blocks (16 units each)
#define NB2  64             // layer-2 GEMM blocks (8 units each, K=1024)
#define NBO  2              // trailing output blocks
#define NBLK (NB1 + NB2 + NBO)   // 98

typedef _Float16 f16;
typedef f16   half8 __attribute__((ext_vector_type(8)));
typedef float f32x4 __attribute__((ext_vector_type(4)));
typedef unsigned long long ull;

// ---- ws layout (float offsets) ----
// AW1: [128 mt][16 ks][2 spl][64 lane][8] halfs   (A-fragments of packed W_hh1)
// AW2: [128 mt][32 ks][2 spl][64 lane][8] halfs   (packed [W_ih2 | W_hh2], K=1024)
// H planes: fragment-interleaved f16, 4-deep ring: [par 0..3][spl][(nt*16+ks)*64+lane][8]
//   element (b,u): nt=b>>4, ks=u>>5, lane=((u>>3)&3)*16+(b&15), j=u&7
#define AW1_OFF 0
#define AW2_OFF (AW1_OFF + 1048576)
#define B1P_OFF (AW2_OFF + 2097152)
#define B2P_OFF (B1P_OFF + 2048)
#define WX1_OFF (B2P_OFF + 2048)
#define XT_OFF  (WX1_OFF + 2048)      // [512 t][128 b] f32
#define H1P_OFF (XT_OFF + 65536)      // 4 par x 2 spl x 65536 f16 = 262144 floats
#define H2P_OFF (H1P_OFF + 262144)
#define ARR_OFF (H2P_OFF + 262144)    // flags: f1@+0 (32), f2@+64 (64), fo@+128 (2)
#define WS_FLOATS (ARR_OFF + 256)

__device__ __forceinline__ float sigm(float v) { return 1.0f / (1.0f + __expf(-v)); }
__device__ __forceinline__ float tanh_fast(float v) {
    v = fminf(fmaxf(v, -20.0f), 20.0f);
    float e = __expf(2.0f * v);
    return (e - 1.0f) / (e + 1.0f);
}

// agent-scope relaxed store (write-through at LLC) for cross-block h publication
__device__ __forceinline__ void cohstoreh(unsigned short* p, f16 v) {
    unsigned short b = __builtin_bit_cast(unsigned short, v);
    __hip_atomic_store(p, b, __ATOMIC_RELAXED, __HIP_MEMORY_SCOPE_AGENT);
}
__device__ __forceinline__ unsigned cohloadu(const unsigned* p) {
    return __hip_atomic_load(p, __ATOMIC_RELAXED, __HIP_MEMORY_SCOPE_AGENT);
}

// ---------- prep ----------
__global__ void lstm_prep(const float* __restrict__ x,
                          const float* __restrict__ W_ih1, const float* __restrict__ W_hh1,
                          const float* __restrict__ b_ih1, const float* __restrict__ b_hh1,
                          const float* __restrict__ W_ih2, const float* __restrict__ W_hh2,
                          const float* __restrict__ b_ih2, const float* __restrict__ b_hh2,
                          float* __restrict__ ws) {
    int i = blockIdx.x * blockDim.x + threadIdx.x;
    f16* aw1 = (f16*)(ws + AW1_OFF);
    f16* aw2 = (f16*)(ws + AW2_OFF);

    if (i < 131072) {                         // AW1
        int mt = i >> 10, rest = i & 1023, ks = rest >> 6, lane = rest & 63;
        int m = mt * 16 + (lane & 15);
        int u = m >> 2, g = m & 3;
        int kbase = ks * 32 + (lane >> 4) * 8;
        size_t ohi = ((((size_t)mt * 16 + ks) * 2 + 0) * 64 + lane) * 8;
        size_t olo = ((((size_t)mt * 16 + ks) * 2 + 1) * 64 + lane) * 8;
        #pragma unroll
        for (int j = 0; j < 8; ++j) {
            float wv = W_hh1[(size_t)(g * Hdim + u) * Hdim + kbase + j];
            f16 hi = (f16)wv;
            f16 lo = (f16)(wv - (float)hi);
            aw1[ohi + j] = hi; aw1[olo + j] = lo;
        }
    }
    if (i >= 131072 && i < 393216) {          // AW2 (K=1024 concat)
        int i2 = i - 131072;
        int mt = i2 >> 11, rest = i2 & 2047, ks = rest >> 6, lane = rest & 63;
        int m = mt * 16 + (lane & 15);
        int u = m >> 2, g = m & 3;
        int kbase = ks * 32 + (lane >> 4) * 8;
        size_t ohi = ((((size_t)mt * 32 + ks) * 2 + 0) * 64 + lane) * 8;
        size_t olo = ((((size_t)mt * 32 + ks) * 2 + 1) * 64 + lane) * 8;
        #pragma unroll
        for (int j = 0; j < 8; ++j) {
            int k = kbase + j;
            float wv = (k < Hdim) ? W_ih2[(size_t)(g * Hdim + u) * Hdim + k]
                                  : W_hh2[(size_t)(g * Hdim + u) * Hdim + (k - Hdim)];
            f16 hi = (f16)wv;
            f16 lo = (f16)(wv - (float)hi);
            aw2[ohi + j] = hi; aw2[olo + j] = lo;
        }
    }
    if (i < Hdim) {
        float4 bb1 = { b_ih1[i] + b_hh1[i],               b_ih1[Hdim+i] + b_hh1[Hdim+i],
                       b_ih1[2*Hdim+i] + b_hh1[2*Hdim+i], b_ih1[3*Hdim+i] + b_hh1[3*Hdim+i] };
        float4 bb2 = { b_ih2[i] + b_hh2[i],               b_ih2[Hdim+i] + b_hh2[Hdim+i],
                       b_ih2[2*Hdim+i] + b_hh2[2*Hdim+i], b_ih2[3*Hdim+i] + b_hh2[3*Hdim+i] };
        float4 wx  = { W_ih1[i], W_ih1[Hdim+i], W_ih1[2*Hdim+i], W_ih1[3*Hdim+i] };
        ((float4*)(ws + B1P_OFF))[i] = bb1;
        ((float4*)(ws + B2P_OFF))[i] = bb2;
        ((float4*)(ws + WX1_OFF))[i] = wx;
    }
    if (i < Tdim * Bdim) {
        int t = i >> 7, b = i & 127;
        ws[XT_OFF + i] = x[b * Tdim + t];
    }
    if (i < 131072) {                          // zero all 4 parities x 2 spl of h1,h2
        ((ull*)(ws + H1P_OFF))[i] = 0;
        ((ull*)(ws + H2P_OFF))[i] = 0;
    }
    if (i < 256) ((unsigned*)(ws + ARR_OFF))[i] = 0u;
}

// ---------- persistent MFMA main kernel (flag-array async pipeline) ----------
__global__ __launch_bounds__(256, 1) void lstm_main(float* ws,
                                                    const float* __restrict__ Wout,
                                                    const float* __restrict__ bout,
                                                    float* __restrict__ out) {
    const int tid  = threadIdx.x, bid = blockIdx.x;
    const int w    = tid >> 6;
    const int lane = tid & 63;
    const int quad = lane >> 4;
    const int col  = lane & 15;
    const bool is1  = (bid < NB1);
    const bool is2  = (bid >= NB1) && (bid < NB1 + NB2);
    const bool isout = (bid >= NB1 + NB2);

    __shared__ f16   awlds[65536];       // 128 KB weight A-fragments
    __shared__ float wout_lds[Hdim];
    __shared__ float psum[2][128];
    __shared__ float xflds[128];
    __shared__ float qpart[4][64];

    unsigned* flg = (unsigned*)(ws + ARR_OFF);   // f1@0(32) f2@64(64) fo@128(2)
    const float* xT = ws + XT_OFF;
    const float bout0 = bout[0];

    // ---- wait: one wave polls all three flag arrays; T==0 is trivially true ----
    auto wait3 = [&](unsigned T1, unsigned T2, unsigned To) {
        if (tid < 64) {
            const unsigned sent = 0xFFFFFFFFu;
            for (;;) {
                unsigned v1 = (lane < 32) ? cohloadu(flg + lane)       : sent;
                unsigned v2 =               cohloadu(flg + 64 + lane);
                unsigned vo = (lane < 2)  ? cohloadu(flg + 128 + lane) : sent;
                if (__all(v1 >= T1 && v2 >= T2 && vo >= To)) break;
                __builtin_amdgcn_s_sleep(1);
            }
            __builtin_amdgcn_fence(__ATOMIC_ACQUIRE, "agent");   // inv L1 + XCD-L2
        }
        __syncthreads();
    };
    // ---- arrive: drain stores (syncthreads -> vmcnt0), then own-slot store (no RMW)
    auto post = [&](unsigned* slot, unsigned val) {
        __syncthreads();
        if (tid == 0)
            __hip_atomic_store(slot, val, __ATOMIC_RELAXED, __HIP_MEMORY_SCOPE_AGENT);
    };

    // fragment-plane accessors (PLAIN loads -> L2-cached; acquire-inv per step)
    auto h1pl = [&](int par, int spl) {
        return (const half8*)((const unsigned short*)(ws + H1P_OFF) + (size_t)(par*2+spl) * 65536); };
    auto h2pl = [&](int par, int spl) {
        return (const half8*)((const unsigned short*)(ws + H2P_OFF) + (size_t)(par*2+spl) * 65536); };
    auto h1st = [&](int par, int spl) {
        return (unsigned short*)(ws + H1P_OFF) + (size_t)(par*2+spl) * 65536; };
    auto h2st = [&](int par, int spl) {
        return (unsigned short*)(ws + H2P_OFF) + (size_t)(par*2+spl) * 65536; };

    // ---- one-time: weight slice -> LDS
    if (!isout) {
        half8* d = (half8*)awlds;
        const half8* s = (const half8*)(ws + (is1 ? AW1_OFF : AW2_OFF))
                       + (size_t)(is1 ? bid : bid - NB1) * 8192;
        for (int i = tid; i < 8192; i += 256) d[i] = s[i];
    }
    wout_lds[tid]       = Wout[tid];
    wout_lds[256 + tid] = Wout[256 + tid];
    __syncthreads();
    const half8* aw8 = (const half8*)awlds;

    int b_[2] = { w * 32 + col, w * 32 + 16 + col };
    const int nt0 = 2 * w, nt1 = 2 * w + 1;
    int   u_[4];  float4 b1v[4], wxv[4];  float c1s[4][2];  int h1off[4][2];
    int   u2_[2]; float4 b2v[2];          float c2s[2][2];  int h2off[2][2];
    if (is1) {
        #pragma unroll
        for (int mt = 0; mt < 4; ++mt) {
            u_[mt]  = bid * 16 + mt * 4 + quad;
            b1v[mt] = ((const float4*)(ws + B1P_OFF))[u_[mt]];
            wxv[mt] = ((const float4*)(ws + WX1_OFF))[u_[mt]];
            c1s[mt][0] = c1s[mt][1] = 0.0f;
            #pragma unroll
            for (int nt = 0; nt < 2; ++nt) {
                int b = b_[nt], u = u_[mt];
                h1off[mt][nt] = ((((b>>4)*16 + (u>>5))*64) + (((u>>3)&3)*16 + (b&15)))*8 + (u&7);
            }
        }
    } else if (is2) {
        #pragma unroll
        for (int mt = 0; mt < 2; ++mt) {
            u2_[mt] = (bid - NB1) * 8 + mt * 4 + quad;
            b2v[mt] = ((const float4*)(ws + B2P_OFF))[u2_[mt]];
            c2s[mt][0] = c2s[mt][1] = 0.0f;
            #pragma unroll
            for (int nt = 0; nt < 2; ++nt) {
                int b = b_[nt], u = u2_[mt];
                h2off[mt][nt] = ((((b>>4)*16 + (u>>5))*64) + (((u>>3)&3)*16 + (b&15)))*8 + (u&7);
            }
        }
    }

    // ---- layer-1: gates = Whi·hhi + Wlo·hhi + Whi·hlo + wx·x + b1 (8-deep ring)
    auto gemm1 = [&](int spar, int dpar, float xv0, float xv1) {
        f32x4 acc[4][2] = {};
        const half8* fh = h1pl(spar, 0);
        const half8* fl = h1pl(spar, 1);
        half8 bh[8][2], bl[8][2];
        #pragma unroll
        for (int ks = 0; ks < 8; ++ks) {
            bh[ks][0] = fh[(nt0*16+ks)*64 + lane]; bh[ks][1] = fh[(nt1*16+ks)*64 + lane];
            bl[ks][0] = fl[(nt0*16+ks)*64 + lane]; bl[ks][1] = fl[(nt1*16+ks)*64 + lane];
        }
        #pragma unroll
        for (int ks = 0; ks < 16; ++ks) {
            half8 b0h = bh[ks&7][0], b1h = bh[ks&7][1];
            half8 b0l = bl[ks&7][0], b1l = bl[ks&7][1];
            if (ks < 8) {
                int kp = ks + 8;
                bh[ks&7][0] = fh[(nt0*16+kp)*64 + lane]; bh[ks&7][1] = fh[(nt1*16+kp)*64 + lane];
                bl[ks&7][0] = fl[(nt0*16+kp)*64 + lane]; bl[ks&7][1] = fl[(nt1*16+kp)*64 + lane];
            }
            #pragma unroll
            for (int mt = 0; mt < 4; ++mt) {
                half8 ah = aw8[((mt*16 + ks)*2 + 0)*64 + lane];
                half8 al = aw8[((mt*16 + ks)*2 + 1)*64 + lane];
                acc[mt][0] = __builtin_amdgcn_mfma_f32_16x16x32_f16(ah, b0h, acc[mt][0], 0, 0, 0);
                acc[mt][0] = __builtin_amdgcn_mfma_f32_16x16x32_f16(al, b0h, acc[mt][0], 0, 0, 0);
                acc[mt][0] = __builtin_amdgcn_mfma_f32_16x16x32_f16(ah, b0l, acc[mt][0], 0, 0, 0);
                acc[mt][1] = __builtin_amdgcn_mfma_f32_16x16x32_f16(ah, b1h, acc[mt][1], 0, 0, 0);
                acc[mt][1] = __builtin_amdgcn_mfma_f32_16x16x32_f16(al, b1h, acc[mt][1], 0, 0, 0);
                acc[mt][1] = __builtin_amdgcn_mfma_f32_16x16x32_f16(ah, b1l, acc[mt][1], 0, 0, 0);
            }
        }
        float xv[2] = { xv0, xv1 };
        #pragma unroll
        for (int mt = 0; mt < 4; ++mt)
            #pragma unroll
            for (int nt = 0; nt < 2; ++nt) {
                f32x4 g = acc[mt][nt];
                float pi = g[0] + b1v[mt].x + wxv[mt].x * xv[nt];
                float pf = g[1] + b1v[mt].y + wxv[mt].y * xv[nt];
                float pg = g[2] + b1v[mt].z + wxv[mt].z * xv[nt];
                float po = g[3] + b1v[mt].w + wxv[mt].w * xv[nt];
                float c = fmaf(sigm(pf), c1s[mt][nt], sigm(pi) * tanh_fast(pg));
                c1s[mt][nt] = c;
                float hv = sigm(po) * tanh_fast(c);
                f16 hhi = (f16)hv;
                f16 hlo = (f16)(hv - (float)hhi);
                cohstoreh(h1st(dpar,0) + h1off[mt][nt], hhi);
                cohstoreh(h1st(dpar,1) + h1off[mt][nt], hlo);
            }
    };

    // ---- layer-2: gates = W2·[h1(s); h2(s-1)] (3-term, 8-deep ring)
    auto gemm2 = [&](int s) {
        int cpar = s & 3, ppar = (s - 1) & 3;
        f32x4 acc[2][2] = {};
        const half8* fh = h1pl(cpar, 0);
        const half8* fl = h1pl(cpar, 1);
        const half8* gh = h2pl(ppar, 0);
        const half8* gl = h2pl(ppar, 1);
        half8 bh[8][2], bl[8][2];
        #pragma unroll
        for (int ks = 0; ks < 8; ++ks) {
            bh[ks][0] = fh[(nt0*16+ks)*64 + lane]; bh[ks][1] = fh[(nt1*16+ks)*64 + lane];
            bl[ks][0] = fl[(nt0*16+ks)*64 + lane]; bl[ks][1] = fl[(nt1*16+ks)*64 + lane];
        }
        #pragma unroll
        for (int ks = 0; ks < 32; ++ks) {
            half8 b0h = bh[ks&7][0], b1h = bh[ks&7][1];
            half8 b0l = bl[ks&7][0], b1l = bl[ks&7][1];
            if (ks < 24) {
                int kp = ks + 8;
                const half8* sh = (kp < 16) ? fh : gh;
                const half8* sl = (kp < 16) ? fl : gl;
                int kq = (kp < 16) ? kp : kp - 16;
                bh[ks&7][0] = sh[(nt0*16+kq)*64 + lane]; bh[ks&7][1] = sh[(nt1*16+kq)*64 + lane];
                bl[ks&7][0] = sl[(nt0*16+kq)*64 + lane]; bl[ks&7][1] = sl[(nt1*16+kq)*64 + lane];
            }
            #pragma unroll
            for (int mt = 0; mt < 2; ++mt) {
                half8 ah = aw8[((mt*32 + ks)*2 + 0)*64 + lane];
                half8 al = aw8[((mt*32 + ks)*2 + 1)*64 + lane];
                acc[mt][0] = __builtin_amdgcn_mfma_f32_16x16x32_f16(ah, b0h, acc[mt][0], 0, 0, 0);
                acc[mt][0] = __builtin_amdgcn_mfma_f32_16x16x32_f16(al, b0h, acc[mt][0], 0, 0, 0);
                acc[mt][0] = __builtin_amdgcn_mfma_f32_16x16x32_f16(ah, b0l, acc[mt][0], 0, 0, 0);
                acc[mt][1] = __builtin_amdgcn_mfma_f32_16x16x32_f16(ah, b1h, acc[mt][1], 0, 0, 0);
                acc[mt][1] = __builtin_amdgcn_mfma_f32_16x16x32_f16(al, b1h, acc[mt][1], 0, 0, 0);
                acc[mt][1] = __builtin_amdgcn_mfma_f32_16x16x32_f16(ah, b1l, acc[mt][1], 0, 0, 0);
            }
        }
        #pragma unroll
        for (int mt = 0; mt < 2; ++mt)
            #pragma unroll
            for (int nt = 0; nt < 2; ++nt) {
                f32x4 g = acc[mt][nt];
                float pi = g[0] + b2v[mt].x;
                float pf = g[1] + b2v[mt].y;
                float pg = g[2] + b2v[mt].z;
                float po = g[3] + b2v[mt].w;
                float c = fmaf(sigm(pf), c2s[mt][nt], sigm(pi) * tanh_fast(pg));
                c2s[mt][nt] = c;
                float hv = sigm(po) * tanh_fast(c);
                f16 hhi = (f16)hv;
                f16 hlo = (f16)(hv - (float)hhi);
                cohstoreh(h2st(cpar,0) + h2off[mt][nt], hhi);
                cohstoreh(h2st(cpar,1) + h2off[mt][nt], hlo);
            }
    };

    // ================= GROUP 1: layer-1 recurrence =================
    if (is1) {
        // prologue: h1(0) from x(0) (h1(-1)=0) -> parity 0; f1 = 1
        #pragma unroll
        for (int mt = 0; mt < 4; ++mt)
            #pragma unroll
            for (int nt = 0; nt < 2; ++nt) {
                float xv = xT[b_[nt]];
                float pi = b1v[mt].x + wxv[mt].x * xv;
                float pg = b1v[mt].z + wxv[mt].z * xv;
                float po = b1v[mt].w + wxv[mt].w * xv;
                float c = sigm(pi) * tanh_fast(pg);
                c1s[mt][nt] = c;
                float hv = sigm(po) * tanh_fast(c);
                f16 hhi = (f16)hv;
                f16 hlo = (f16)(hv - (float)hhi);
                cohstoreh(h1st(0,0) + h1off[mt][nt], hhi);
                cohstoreh(h1st(0,1) + h1off[mt][nt], hlo);
            }
        post(&flg[bid], 1u);

        // main: step t publishes h1(t+1); f1 -> t+2
        for (int t = 0; t <= Tdim - 2; ++t) {
            wait3((unsigned)(t + 1), (t >= 3) ? (unsigned)(t - 2) : 0u, 0u);
            gemm1(t & 3, (t + 1) & 3,
                  xT[(t + 1) * Bdim + b_[0]], xT[(t + 1) * Bdim + b_[1]]);
            post(&flg[bid], (unsigned)(t + 2));
        }

        // future: step t computes feedback O(t-1), publishes h1(t); f1 -> t+1
        for (int t = Tdim; t < TT; ++t) {
            wait3((unsigned)t, (unsigned)t, 0u);
            {   // cooperative O(t-1) from h2(t-1) fragments
                int b = tid & 127, kh = tid >> 7;
                int nt = b >> 4, nl = b & 15;
                const half8* ph = h2pl((t - 1) & 3, 0);
                const half8* pl = h2pl((t - 1) & 3, 1);
                float a = 0.0f;
                #pragma unroll
                for (int kk = 0; kk < 8; ++kk) {
                    int ks = kh * 8 + kk;
                    #pragma unroll
                    for (int qd = 0; qd < 4; ++qd) {
                        half8 vh = ph[(nt*16+ks)*64 + qd*16 + nl];
                        half8 vl = pl[(nt*16+ks)*64 + qd*16 + nl];
                        int ub = ks*32 + qd*8;
                        #pragma unroll
                        for (int j = 0; j < 8; ++j)
                            a = fmaf((float)vh[j] + (float)vl[j], wout_lds[ub + j], a);
                    }
                }
                psum[kh][b] = a;
                __syncthreads();
                if (tid < 128) xflds[tid] = psum[0][tid] + psum[1][tid] + bout0;
                __syncthreads();
            }
            gemm1((t - 1) & 3, t & 3, xflds[b_[0]], xflds[b_[1]]);
            post(&flg[bid], (unsigned)(t + 1));
        }
    }
    // ================= GROUP 2: layer-2 (uniform loop) =================
    else if (is2) {
        for (int s = 0; s < TT; ++s) {
            wait3((unsigned)(s + 1), (unsigned)s, (s >= 4) ? (unsigned)(s - 3) : 0u);
            gemm2(s);
            post(&flg[64 + (bid - NB1)], (unsigned)(s + 1));
        }
    }
    // ================= OUT blocks: trail G2 =================
    else {
        int b = (bid - NB1 - NB2) * 64 + lane;
        int nt = b >> 4, nl = b & 15;
        for (int s = 0; s < TT; ++s) {
            wait3(0u, (unsigned)(s + 1), 0u);
            const half8* ph = h2pl(s & 3, 0);
            const half8* pl = h2pl(s & 3, 1);
            float a = 0.0f;
            #pragma unroll
            for (int kk = 0; kk < 4; ++kk) {
                int ks = w * 4 + kk;
                #pragma unroll
                for (int qd = 0; qd < 4; ++qd) {
                    half8 vh = ph[(nt*16+ks)*64 + qd*16 + nl];
                    half8 vl = pl[(nt*16+ks)*64 + qd*16 + nl];
                    int ub = ks*32 + qd*8;
                    #pragma unroll
                    for (int j = 0; j < 8; ++j)
                        a = fmaf((float)vh[j] + (float)vl[j], wout_lds[ub + j], a);
                }
            }
            qpart[w][lane] = a;
            __syncthreads();
            if (w == 0)
                out[(size_t)b * TT + s] = qpart[0][lane] + qpart[1][lane]
                                        + qpart[2][lane] + qpart[3][lane] + bout0;
            post(&flg[128 + (bid - NB1 - NB2)], (unsigned)(s + 1));
        }
    }
}

extern "C" void kernel_launch(void* const* d_in, const int* in_sizes, int n_in,
                              void* d_out, int out_size, void* d_ws, size_t ws_size,
                              hipStream_t stream) {
    const float* x     = (const float*)d_in[0];
    const float* W_ih1 = (const float*)d_in[1];
    const float* W_hh1 = (const float*)d_in[2];
    const float* b_ih1 = (const float*)d_in[3];
    const float* b_hh1 = (const float*)d_in[4];
    const float* W_ih2 = (const float*)d_in[5];
    const float* W_hh2 = (const float*)d_in[6];
    const float* b_ih2 = (const float*)d_in[7];
    const float* b_hh2 = (const float*)d_in[8];
    const float* W_out = (const float*)d_in[9];
    const float* b_out = (const float*)d_in[10];
    float* ws  = (float*)d_ws;
    float* out = (float*)d_out;

    hipLaunchKernelGGL(lstm_prep, dim3(1536), dim3(256), 0, stream,
                       x, W_ih1, W_hh1, b_ih1, b_hh1, W_ih2, W_hh2, b_ih2, b_hh2, ws);
    hipLaunchKernelGGL(lstm_main, dim3(NBLK), dim3(256), 0, stream,
                       ws, W_out, b_out, out);
}

// Round 10
// 6861.243 us; speedup vs baseline: 4.4718x; 1.2348x over previous
//
#include <hip/hip_runtime.h>
#include <cstdint>

// ---- problem dims ----
#define Hdim 512
#define Bdim 128
#define Tdim 512
#define FUT  32
#define TT   (Tdim + FUT)   // 544
#define NB1  32             // layer-1 GEMM blocks (16 units each)
#define NB2  64             // layer-2 GEMM blocks (8 units each, K=1024)
#define NBO  2              // trailing output blocks
#define NBLK (NB1 + NB2 + NBO)   // 98

typedef _Float16 f16;
typedef f16   half8 __attribute__((ext_vector_type(8)));
typedef float f32x4 __attribute__((ext_vector_type(4)));
typedef unsigned long long ull;

// ---- ws layout (float offsets) ----
// AW1: [128 mt][16 ks][2 spl][64 lane][8] halfs   (A-fragments of packed W_hh1)
// AW2: [128 mt][32 ks][2 spl][64 lane][8] halfs   (packed [W_ih2 | W_hh2], K=1024)
// H planes: fragment-interleaved f16, 4-deep ring: [par 0..3][spl][(nt*16+ks)*64+lane][8]
//   element (b,u): nt=b>>4, ks=u>>5, lane=((u>>3)&3)*16+(b&15), j=u&7
#define AW1_OFF 0
#define AW2_OFF (AW1_OFF + 1048576)
#define B1P_OFF (AW2_OFF + 2097152)
#define B2P_OFF (B1P_OFF + 2048)
#define WX1_OFF (B2P_OFF + 2048)
#define XT_OFF  (WX1_OFF + 2048)      // [512 t][128 b] f32
#define H1P_OFF (XT_OFF + 65536)      // 4 par x 2 spl x 65536 f16 = 262144 floats
#define H2P_OFF (H1P_OFF + 262144)
#define ARR_OFF (H2P_OFF + 262144)    // flags: f1@+0 (32), f2@+64 (64), fo@+128 (2)
#define WS_FLOATS (ARR_OFF + 256)

__device__ __forceinline__ float sigm(float v) { return 1.0f / (1.0f + __expf(-v)); }
__device__ __forceinline__ float tanh_fast(float v) {
    v = fminf(fmaxf(v, -20.0f), 20.0f);
    float e = __expf(2.0f * v);
    return (e - 1.0f) / (e + 1.0f);
}

__device__ __forceinline__ unsigned cohloadu(const unsigned* p) {
    return __hip_atomic_load(p, __ATOMIC_RELAXED, __HIP_MEMORY_SCOPE_AGENT);
}
__device__ __forceinline__ void cohstore64(ull* p, ull v) {
    __hip_atomic_store(p, v, __ATOMIC_RELAXED, __HIP_MEMORY_SCOPE_AGENT);
}

// ---------- prep (unchanged layouts) ----------
__global__ void lstm_prep(const float* __restrict__ x,
                          const float* __restrict__ W_ih1, const float* __restrict__ W_hh1,
                          const float* __restrict__ b_ih1, const float* __restrict__ b_hh1,
                          const float* __restrict__ W_ih2, const float* __restrict__ W_hh2,
                          const float* __restrict__ b_ih2, const float* __restrict__ b_hh2,
                          float* __restrict__ ws) {
    int i = blockIdx.x * blockDim.x + threadIdx.x;
    f16* aw1 = (f16*)(ws + AW1_OFF);
    f16* aw2 = (f16*)(ws + AW2_OFF);

    if (i < 131072) {                         // AW1
        int mt = i >> 10, rest = i & 1023, ks = rest >> 6, lane = rest & 63;
        int m = mt * 16 + (lane & 15);
        int u = m >> 2, g = m & 3;
        int kbase = ks * 32 + (lane >> 4) * 8;
        size_t ohi = ((((size_t)mt * 16 + ks) * 2 + 0) * 64 + lane) * 8;
        size_t olo = ((((size_t)mt * 16 + ks) * 2 + 1) * 64 + lane) * 8;
        #pragma unroll
        for (int j = 0; j < 8; ++j) {
            float wv = W_hh1[(size_t)(g * Hdim + u) * Hdim + kbase + j];
            f16 hi = (f16)wv;
            f16 lo = (f16)(wv - (float)hi);
            aw1[ohi + j] = hi; aw1[olo + j] = lo;
        }
    }
    if (i >= 131072 && i < 393216) {          // AW2 (K=1024 concat)
        int i2 = i - 131072;
        int mt = i2 >> 11, rest = i2 & 2047, ks = rest >> 6, lane = rest & 63;
        int m = mt * 16 + (lane & 15);
        int u = m >> 2, g = m & 3;
        int kbase = ks * 32 + (lane >> 4) * 8;
        size_t ohi = ((((size_t)mt * 32 + ks) * 2 + 0) * 64 + lane) * 8;
        size_t olo = ((((size_t)mt * 32 + ks) * 2 + 1) * 64 + lane) * 8;
        #pragma unroll
        for (int j = 0; j < 8; ++j) {
            int k = kbase + j;
            float wv = (k < Hdim) ? W_ih2[(size_t)(g * Hdim + u) * Hdim + k]
                                  : W_hh2[(size_t)(g * Hdim + u) * Hdim + (k - Hdim)];
            f16 hi = (f16)wv;
            f16 lo = (f16)(wv - (float)hi);
            aw2[ohi + j] = hi; aw2[olo + j] = lo;
        }
    }
    if (i < Hdim) {
        float4 bb1 = { b_ih1[i] + b_hh1[i],               b_ih1[Hdim+i] + b_hh1[Hdim+i],
                       b_ih1[2*Hdim+i] + b_hh1[2*Hdim+i], b_ih1[3*Hdim+i] + b_hh1[3*Hdim+i] };
        float4 bb2 = { b_ih2[i] + b_hh2[i],               b_ih2[Hdim+i] + b_hh2[Hdim+i],
                       b_ih2[2*Hdim+i] + b_hh2[2*Hdim+i], b_ih2[3*Hdim+i] + b_hh2[3*Hdim+i] };
        float4 wx  = { W_ih1[i], W_ih1[Hdim+i], W_ih1[2*Hdim+i], W_ih1[3*Hdim+i] };
        ((float4*)(ws + B1P_OFF))[i] = bb1;
        ((float4*)(ws + B2P_OFF))[i] = bb2;
        ((float4*)(ws + WX1_OFF))[i] = wx;
    }
    if (i < Tdim * Bdim) {
        int t = i >> 7, b = i & 127;
        ws[XT_OFF + i] = x[b * Tdim + t];
    }
    if (i < 131072) {
        ((ull*)(ws + H1P_OFF))[i] = 0;
        ((ull*)(ws + H2P_OFF))[i] = 0;
    }
    if (i < 256) ((unsigned*)(ws + ARR_OFF))[i] = 0u;
}

// ---------- persistent MFMA main kernel ----------
__global__ __launch_bounds__(256, 1) void lstm_main(float* ws,
                                                    const float* __restrict__ Wout,
                                                    const float* __restrict__ bout,
                                                    float* __restrict__ out) {
    const int tid  = threadIdx.x, bid = blockIdx.x;
    const int w    = tid >> 6;
    const int lane = tid & 63;
    const int quad = lane >> 4;
    const int col  = lane & 15;
    const bool is1  = (bid < NB1);
    const bool is2  = (bid >= NB1) && (bid < NB1 + NB2);
    const bool isout = (bid >= NB1 + NB2);

    __shared__ f16   awlds[65536];       // 128 KB weight A-fragments
    __shared__ float wout_lds[Hdim];
    __shared__ float psum[2][128];
    __shared__ float xflds[128];
    __shared__ float qpart[4][64];
    __shared__ ull   hstg[1024];         // 8 KB coalesced-store staging

    unsigned* flg = (unsigned*)(ws + ARR_OFF);   // f1@0(32) f2@64(64) fo@128(2)
    unsigned short* stg = (unsigned short*)hstg;
    const float* xT = ws + XT_OFF;
    const float bout0 = bout[0];

    // ---- waits ----
    auto wait1 = [&](unsigned T1) {                    // f1 only (no fence)
        if (tid < 64) {
            for (;;) {
                unsigned v1 = (lane < 32) ? cohloadu(flg + lane) : 0xFFFFFFFFu;
                if (__all(v1 >= T1)) break;
                __builtin_amdgcn_s_sleep(1);
            }
        }
        __syncthreads();
    };
    auto wait2o = [&](unsigned T2, unsigned To) {      // f2 + fo, then acquire fence
        if (tid < 64) {
            for (;;) {
                unsigned v2 =              cohloadu(flg + 64 + lane);
                unsigned vo = (lane < 2) ? cohloadu(flg + 128 + lane) : 0xFFFFFFFFu;
                if (__all(v2 >= T2 && vo >= To)) break;
                __builtin_amdgcn_s_sleep(1);
            }
            __builtin_amdgcn_fence(__ATOMIC_ACQUIRE, "agent");
        }
        __syncthreads();
    };
    auto wait3 = [&](unsigned T1, unsigned T2, unsigned To) {  // all three + fence
        if (tid < 64) {
            const unsigned sent = 0xFFFFFFFFu;
            for (;;) {
                unsigned v1 = (lane < 32) ? cohloadu(flg + lane)       : sent;
                unsigned v2 =               cohloadu(flg + 64 + lane);
                unsigned vo = (lane < 2)  ? cohloadu(flg + 128 + lane) : sent;
                if (__all(v1 >= T1 && v2 >= T2 && vo >= To)) break;
                __builtin_amdgcn_s_sleep(1);
            }
            __builtin_amdgcn_fence(__ATOMIC_ACQUIRE, "agent");
        }
        __syncthreads();
    };
    auto post = [&](unsigned* slot, unsigned val) {    // drain stores then own-slot store
        __syncthreads();
        if (tid == 0)
            __hip_atomic_store(slot, val, __ATOMIC_RELAXED, __HIP_MEMORY_SCOPE_AGENT);
    };

    auto h1pl = [&](int par, int spl) {
        return (const half8*)((const unsigned short*)(ws + H1P_OFF) + (size_t)(par*2+spl) * 65536); };
    auto h2pl = [&](int par, int spl) {
        return (const half8*)((const unsigned short*)(ws + H2P_OFF) + (size_t)(par*2+spl) * 65536); };
    auto h1ull = [&](int par, int spl) {
        return (ull*)(ws + H1P_OFF) + (size_t)(par*2+spl) * 16384; };
    auto h2ull = [&](int par, int spl) {
        return (ull*)(ws + H2P_OFF) + (size_t)(par*2+spl) * 16384; };

    // ---- one-time: weight slice -> LDS
    if (!isout) {
        half8* d = (half8*)awlds;
        const half8* s = (const half8*)(ws + (is1 ? AW1_OFF : AW2_OFF))
                       + (size_t)(is1 ? bid : bid - NB1) * 8192;
        for (int i = tid; i < 8192; i += 256) d[i] = s[i];
    }
    wout_lds[tid]       = Wout[tid];
    wout_lds[256 + tid] = Wout[256 + tid];
    __syncthreads();
    const half8* aw8 = (const half8*)awlds;

    int b_[2] = { w * 32 + col, w * 32 + 16 + col };
    const int nt0 = 2 * w, nt1 = 2 * w + 1;
    int   u_[4];  float4 b1v[4], wxv[4];  float c1s[4][2];
    int   u2_[2]; float4 b2v[2];          float c2s[2][2];
    const int ks1 = bid >> 1, q0 = (bid & 1) * 2;            // G1 store geometry
    const int gid = bid - NB1;
    const int ks2 = gid >> 2, qg = gid & 3;                  // G2 store geometry
    if (is1) {
        #pragma unroll
        for (int mt = 0; mt < 4; ++mt) {
            u_[mt]  = bid * 16 + mt * 4 + quad;
            b1v[mt] = ((const float4*)(ws + B1P_OFF))[u_[mt]];
            wxv[mt] = ((const float4*)(ws + WX1_OFF))[u_[mt]];
            c1s[mt][0] = c1s[mt][1] = 0.0f;
        }
    } else if (is2) {
        #pragma unroll
        for (int mt = 0; mt < 2; ++mt) {
            u2_[mt] = gid * 8 + mt * 4 + quad;
            b2v[mt] = ((const float4*)(ws + B2P_OFF))[u2_[mt]];
            c2s[mt][0] = c2s[mt][1] = 0.0f;
        }
    }

    // ---- G1 coalesced publish: stage LDS -> 4 b64 agent stores/thread
    auto store1 = [&](int dpar) {
        __syncthreads();                                     // staging visible
        #pragma unroll
        for (int k = 0; k < 4; ++k) {
            int f = k * 256 + tid;                           // 0..1023 flat ull
            int spl = f >> 9, rest = f & 511, ntg = rest >> 6, pos = rest & 63;
            cohstore64(h1ull(dpar, spl) + ((ntg*16 + ks1)*64 + q0*16)*2 + pos, hstg[f]);
        }
    };
    auto stage1 = [&](int mt, int ntl, float hv) {
        f16 hhi = (f16)hv;
        f16 hlo = (f16)(hv - (float)hhi);
        int ntg = 2*w + ntl, mq = mt*4 + quad;
        int idx = ((ntg*32) + (mq>>3)*16 + col)*8 + (mq&7);
        stg[idx]        = __builtin_bit_cast(unsigned short, hhi);
        stg[2048 + idx] = __builtin_bit_cast(unsigned short, hlo);
    };

    // ---- layer-1 step: gates = Whi·hhi + Wlo·hhi + Whi·hlo + wx·x + b1
    auto gemm1 = [&](int spar, int dpar, float xv0, float xv1) {
        f32x4 acc[4][2] = {};
        const half8* fh = h1pl(spar, 0);
        const half8* fl = h1pl(spar, 1);
        half8 bh[8][2], bl[8][2];
        #pragma unroll
        for (int ks = 0; ks < 8; ++ks) {
            bh[ks][0] = fh[(nt0*16+ks)*64 + lane]; bh[ks][1] = fh[(nt1*16+ks)*64 + lane];
            bl[ks][0] = fl[(nt0*16+ks)*64 + lane]; bl[ks][1] = fl[(nt1*16+ks)*64 + lane];
        }
        #pragma unroll
        for (int ks = 0; ks < 16; ++ks) {
            half8 b0h = bh[ks&7][0], b1h = bh[ks&7][1];
            half8 b0l = bl[ks&7][0], b1l = bl[ks&7][1];
            if (ks < 8) {
                int kp = ks + 8;
                bh[ks&7][0] = fh[(nt0*16+kp)*64 + lane]; bh[ks&7][1] = fh[(nt1*16+kp)*64 + lane];
                bl[ks&7][0] = fl[(nt0*16+kp)*64 + lane]; bl[ks&7][1] = fl[(nt1*16+kp)*64 + lane];
            }
            #pragma unroll
            for (int mt = 0; mt < 4; ++mt) {
                half8 ah = aw8[((mt*16 + ks)*2 + 0)*64 + lane];
                half8 al = aw8[((mt*16 + ks)*2 + 1)*64 + lane];
                acc[mt][0] = __builtin_amdgcn_mfma_f32_16x16x32_f16(ah, b0h, acc[mt][0], 0, 0, 0);
                acc[mt][0] = __builtin_amdgcn_mfma_f32_16x16x32_f16(al, b0h, acc[mt][0], 0, 0, 0);
                acc[mt][0] = __builtin_amdgcn_mfma_f32_16x16x32_f16(ah, b0l, acc[mt][0], 0, 0, 0);
                acc[mt][1] = __builtin_amdgcn_mfma_f32_16x16x32_f16(ah, b1h, acc[mt][1], 0, 0, 0);
                acc[mt][1] = __builtin_amdgcn_mfma_f32_16x16x32_f16(al, b1h, acc[mt][1], 0, 0, 0);
                acc[mt][1] = __builtin_amdgcn_mfma_f32_16x16x32_f16(ah, b1l, acc[mt][1], 0, 0, 0);
            }
        }
        float xv[2] = { xv0, xv1 };
        #pragma unroll
        for (int mt = 0; mt < 4; ++mt)
            #pragma unroll
            for (int nt = 0; nt < 2; ++nt) {
                f32x4 g = acc[mt][nt];
                float pi = g[0] + b1v[mt].x + wxv[mt].x * xv[nt];
                float pf = g[1] + b1v[mt].y + wxv[mt].y * xv[nt];
                float pg = g[2] + b1v[mt].z + wxv[mt].z * xv[nt];
                float po = g[3] + b1v[mt].w + wxv[mt].w * xv[nt];
                float c = fmaf(sigm(pf), c1s[mt][nt], sigm(pi) * tanh_fast(pg));
                c1s[mt][nt] = c;
                stage1(mt, nt, sigm(po) * tanh_fast(c));
            }
        store1(dpar);
    };

    // ---- layer-2 step with cross-wait prefetch ----
    auto g2_step = [&](int s) {
        int cpar = s & 3, ppar = (s - 1) & 3;
        const half8* fh = h1pl(cpar, 0);
        const half8* fl = h1pl(cpar, 1);
        const half8* gh = h2pl(ppar, 0);
        const half8* gl = h2pl(ppar, 1);

        wait1((unsigned)(s + 1));                   // h1(s) published (usually instant)
        half8 bh[8][2], bl[8][2];
        #pragma unroll
        for (int ks = 0; ks < 8; ++ks) {            // prefetch h1-half first batch
            bh[ks][0] = fh[(nt0*16+ks)*64 + lane]; bh[ks][1] = fh[(nt1*16+ks)*64 + lane];
            bl[ks][0] = fl[(nt0*16+ks)*64 + lane]; bl[ks][1] = fl[(nt1*16+ks)*64 + lane];
        }
        wait2o((unsigned)s, (s >= 4) ? (unsigned)(s - 3) : 0u);   // real wait + fence

        f32x4 acc[2][2] = {};
        #pragma unroll
        for (int ks = 0; ks < 32; ++ks) {
            half8 b0h = bh[ks&7][0], b1h = bh[ks&7][1];
            half8 b0l = bl[ks&7][0], b1l = bl[ks&7][1];
            if (ks < 24) {
                int kp = ks + 8;
                const half8* sh = (kp < 16) ? fh : gh;
                const half8* sl = (kp < 16) ? fl : gl;
                int kq = (kp < 16) ? kp : kp - 16;
                bh[ks&7][0] = sh[(nt0*16+kq)*64 + lane]; bh[ks&7][1] = sh[(nt1*16+kq)*64 + lane];
                bl[ks&7][0] = sl[(nt0*16+kq)*64 + lane]; bl[ks&7][1] = sl[(nt1*16+kq)*64 + lane];
            }
            #pragma unroll
            for (int mt = 0; mt < 2; ++mt) {
                half8 ah = aw8[((mt*32 + ks)*2 + 0)*64 + lane];
                half8 al = aw8[((mt*32 + ks)*2 + 1)*64 + lane];
                acc[mt][0] = __builtin_amdgcn_mfma_f32_16x16x32_f16(ah, b0h, acc[mt][0], 0, 0, 0);
                acc[mt][0] = __builtin_amdgcn_mfma_f32_16x16x32_f16(al, b0h, acc[mt][0], 0, 0, 0);
                acc[mt][0] = __builtin_amdgcn_mfma_f32_16x16x32_f16(ah, b0l, acc[mt][0], 0, 0, 0);
                acc[mt][1] = __builtin_amdgcn_mfma_f32_16x16x32_f16(ah, b1h, acc[mt][1], 0, 0, 0);
                acc[mt][1] = __builtin_amdgcn_mfma_f32_16x16x32_f16(al, b1h, acc[mt][1], 0, 0, 0);
                acc[mt][1] = __builtin_amdgcn_mfma_f32_16x16x32_f16(ah, b1l, acc[mt][1], 0, 0, 0);
            }
        }
        // epilogue: stage hi/lo then coalesced publish (2 b64 stores/thread)
        #pragma unroll
        for (int mt = 0; mt < 2; ++mt)
            #pragma unroll
            for (int nt = 0; nt < 2; ++nt) {
                f32x4 g = acc[mt][nt];
                float pi = g[0] + b2v[mt].x;
                float pf = g[1] + b2v[mt].y;
                float pg = g[2] + b2v[mt].z;
                float po = g[3] + b2v[mt].w;
                float c = fmaf(sigm(pf), c2s[mt][nt], sigm(pi) * tanh_fast(pg));
                c2s[mt][nt] = c;
                float hv = sigm(po) * tanh_fast(c);
                f16 hhi = (f16)hv;
                f16 hlo = (f16)(hv - (float)hhi);
                int ntg = 2*w + nt, mq = mt*4 + quad;
                int idx = ((ntg*16) + col)*8 + mq;
                stg[idx]        = __builtin_bit_cast(unsigned short, hhi);
                stg[1024 + idx] = __builtin_bit_cast(unsigned short, hlo);
            }
        __syncthreads();
        #pragma unroll
        for (int k = 0; k < 2; ++k) {
            int f = k * 256 + tid;                           // 0..511 flat ull
            int spl = f >> 8, rest = f & 255, ntg = rest >> 5, pos = rest & 31;
            cohstore64(h2ull(cpar, spl) + ((ntg*16 + ks2)*64 + qg*16)*2 + pos, hstg[f]);
        }
        post(&flg[64 + gid], (unsigned)(s + 1));
    };

    // ================= GROUP 1 =================
    if (is1) {
        // prologue: h1(0) from x(0) (h1(-1)=0) -> parity 0
        #pragma unroll
        for (int mt = 0; mt < 4; ++mt)
            #pragma unroll
            for (int nt = 0; nt < 2; ++nt) {
                float xv = xT[b_[nt]];
                float pi = b1v[mt].x + wxv[mt].x * xv;
                float pg = b1v[mt].z + wxv[mt].z * xv;
                float po = b1v[mt].w + wxv[mt].w * xv;
                float c = sigm(pi) * tanh_fast(pg);
                c1s[mt][nt] = c;
                stage1(mt, nt, sigm(po) * tanh_fast(c));
            }
        store1(0);
        post(&flg[bid], 1u);

        // main: step t publishes h1(t+1); f1 -> t+2
        for (int t = 0; t <= Tdim - 2; ++t) {
            wait3((unsigned)(t + 1), (t >= 3) ? (unsigned)(t - 2) : 0u, 0u);
            gemm1(t & 3, (t + 1) & 3,
                  xT[(t + 1) * Bdim + b_[0]], xT[(t + 1) * Bdim + b_[1]]);
            post(&flg[bid], (unsigned)(t + 2));
        }

        // future: step t computes feedback O(t-1), publishes h1(t)
        for (int t = Tdim; t < TT; ++t) {
            wait3((unsigned)t, (unsigned)t, 0u);
            {
                int b = tid & 127, kh = tid >> 7;
                int nt = b >> 4, nl = b & 15;
                const half8* ph = h2pl((t - 1) & 3, 0);
                const half8* pl = h2pl((t - 1) & 3, 1);
                float a = 0.0f;
                #pragma unroll
                for (int kk = 0; kk < 8; ++kk) {
                    int ks = kh * 8 + kk;
                    #pragma unroll
                    for (int qd = 0; qd < 4; ++qd) {
                        half8 vh = ph[(nt*16+ks)*64 + qd*16 + nl];
                        half8 vl = pl[(nt*16+ks)*64 + qd*16 + nl];
                        int ub = ks*32 + qd*8;
                        #pragma unroll
                        for (int j = 0; j < 8; ++j)
                            a = fmaf((float)vh[j] + (float)vl[j], wout_lds[ub + j], a);
                    }
                }
                psum[kh][b] = a;
                __syncthreads();
                if (tid < 128) xflds[tid] = psum[0][tid] + psum[1][tid] + bout0;
                __syncthreads();
            }
            gemm1((t - 1) & 3, t & 3, xflds[b_[0]], xflds[b_[1]]);
            post(&flg[bid], (unsigned)(t + 1));
        }
    }
    // ================= GROUP 2 =================
    else if (is2) {
        for (int s = 0; s < TT; ++s) g2_step(s);
    }
    // ================= OUT blocks =================
    else {
        int b = (bid - NB1 - NB2) * 64 + lane;
        int nt = b >> 4, nl = b & 15;
        for (int s = 0; s < TT; ++s) {
            wait3(0u, (unsigned)(s + 1), 0u);
            const half8* ph = h2pl(s & 3, 0);
            const half8* pl = h2pl(s & 3, 1);
            float a = 0.0f;
            #pragma unroll
            for (int kk = 0; kk < 4; ++kk) {
                int ks = w * 4 + kk;
                #pragma unroll
                for (int qd = 0; qd < 4; ++qd) {
                    half8 vh = ph[(nt*16+ks)*64 + qd*16 + nl];
                    half8 vl = pl[(nt*16+ks)*64 + qd*16 + nl];
                    int ub = ks*32 + qd*8;
                    #pragma unroll
                    for (int j = 0; j < 8; ++j)
                        a = fmaf((float)vh[j] + (float)vl[j], wout_lds[ub + j], a);
                }
            }
            qpart[w][lane] = a;
            __syncthreads();
            if (w == 0)
                out[(size_t)b * TT + s] = qpart[0][lane] + qpart[1][lane]
                                        + qpart[2][lane] + qpart[3][lane] + bout0;
            post(&flg[128 + (bid - NB1 - NB2)], (unsigned)(s + 1));
        }
    }
}

extern "C" void kernel_launch(void* const* d_in, const int* in_sizes, int n_in,
                              void* d_out, int out_size, void* d_ws, size_t ws_size,
                              hipStream_t stream) {
    const float* x     = (const float*)d_in[0];
    const float* W_ih1 = (const float*)d_in[1];
    const float* W_hh1 = (const float*)d_in[2];
    const float* b_ih1 = (const float*)d_in[3];
    const float* b_hh1 = (const float*)d_in[4];
    const float* W_ih2 = (const float*)d_in[5];
    const float* W_hh2 = (const float*)d_in[6];
    const float* b_ih2 = (const float*)d_in[7];
    const float* b_hh2 = (const float*)d_in[8];
    const float* W_out = (const float*)d_in[9];
    const float* b_out = (const float*)d_in[10];
    float* ws  = (float*)d_ws;
    float* out = (float*)d_out;

    hipLaunchKernelGGL(lstm_prep, dim3(1536), dim3(256), 0, stream,
                       x, W_ih1, W_hh1, b_ih1, b_hh1, W_ih2, W_hh2, b_ih2, b_hh2, ws);
    hipLaunchKernelGGL(lstm_main, dim3(NBLK), dim3(256), 0, stream,
                       ws, W_out, b_out, out);
}

// Round 11
// 6392.131 us; speedup vs baseline: 4.8000x; 1.0734x over previous
//
#include <hip/hip_runtime.h>
#include <cstdint>

// ---- problem dims ----
#define Hdim 512
#define Bdim 128
#define Tdim 512
#define FUT  32
#define TT   (Tdim + FUT)   // 544
#define NB1  32             // layer-1 GEMM blocks (16 units each)
#define NB2  64             // layer-2 GEMM blocks (8 units each, K=1024)
#define NBO  2              // trailing output blocks
#define NBLK (NB1 + NB2 + NBO)   // 98

typedef _Float16 f16;
typedef f16   half8 __attribute__((ext_vector_type(8)));
typedef float f32x4 __attribute__((ext_vector_type(4)));
typedef unsigned long long ull;

// ---- ws layout (float offsets) ----
// AW1: [128 mt][16 ks][2 spl][64 lane][8] halfs   (A-fragments of packed W_hh1)
// AW2: [128 mt][32 ks][2 spl][64 lane][8] halfs   (packed [W_ih2 | W_hh2], K=1024)
// H planes: fragment-interleaved f16, 4-deep ring: [par 0..3][spl][(nt*16+ks)*64+lane][8]
//   element (b,u): nt=b>>4, ks=u>>5, lane=((u>>3)&3)*16+(b&15), j=u&7
#define AW1_OFF 0
#define AW2_OFF (AW1_OFF + 1048576)
#define B1P_OFF (AW2_OFF + 2097152)
#define B2P_OFF (B1P_OFF + 2048)
#define WX1_OFF (B2P_OFF + 2048)
#define XT_OFF  (WX1_OFF + 2048)      // [512 t][128 b] f32
#define H1P_OFF (XT_OFF + 65536)      // 4 par x 2 spl x 65536 f16 = 262144 floats
#define H2P_OFF (H1P_OFF + 262144)
#define ARR_OFF (H2P_OFF + 262144)    // flags: f1@+0 (32), f2@+64 (64), fo@+128 (2)
#define WS_FLOATS (ARR_OFF + 256)

__device__ __forceinline__ float sigm(float v) { return 1.0f / (1.0f + __expf(-v)); }
__device__ __forceinline__ float tanh_fast(float v) {
    v = fminf(fmaxf(v, -20.0f), 20.0f);
    float e = __expf(2.0f * v);
    return (e - 1.0f) / (e + 1.0f);
}

__device__ __forceinline__ unsigned cohloadu(const unsigned* p) {
    return __hip_atomic_load(p, __ATOMIC_RELAXED, __HIP_MEMORY_SCOPE_AGENT);
}
__device__ __forceinline__ ull cohload64(const ull* p) {
    return __hip_atomic_load(p, __ATOMIC_RELAXED, __HIP_MEMORY_SCOPE_AGENT);
}
__device__ __forceinline__ void cohstore64(ull* p, ull v) {
    __hip_atomic_store(p, v, __ATOMIC_RELAXED, __HIP_MEMORY_SCOPE_AGENT);
}

union HB { ull u[2]; half8 h; };
// LLC-direct 16B fragment load as two contiguous b64 agent loads (line-optimal:
// 64 lanes x 8B consecutive = 4 LLC lines per instruction, no L2 staleness -> NO fences)
__device__ __forceinline__ half8 fragload(const ull* p) {
    HB t; t.u[0] = cohload64(p); t.u[1] = cohload64(p + 1);
    return t.h;
}

// ---------- prep (unchanged layouts) ----------
__global__ void lstm_prep(const float* __restrict__ x,
                          const float* __restrict__ W_ih1, const float* __restrict__ W_hh1,
                          const float* __restrict__ b_ih1, const float* __restrict__ b_hh1,
                          const float* __restrict__ W_ih2, const float* __restrict__ W_hh2,
                          const float* __restrict__ b_ih2, const float* __restrict__ b_hh2,
                          float* __restrict__ ws) {
    int i = blockIdx.x * blockDim.x + threadIdx.x;
    f16* aw1 = (f16*)(ws + AW1_OFF);
    f16* aw2 = (f16*)(ws + AW2_OFF);

    if (i < 131072) {                         // AW1
        int mt = i >> 10, rest = i & 1023, ks = rest >> 6, lane = rest & 63;
        int m = mt * 16 + (lane & 15);
        int u = m >> 2, g = m & 3;
        int kbase = ks * 32 + (lane >> 4) * 8;
        size_t ohi = ((((size_t)mt * 16 + ks) * 2 + 0) * 64 + lane) * 8;
        size_t olo = ((((size_t)mt * 16 + ks) * 2 + 1) * 64 + lane) * 8;
        #pragma unroll
        for (int j = 0; j < 8; ++j) {
            float wv = W_hh1[(size_t)(g * Hdim + u) * Hdim + kbase + j];
            f16 hi = (f16)wv;
            f16 lo = (f16)(wv - (float)hi);
            aw1[ohi + j] = hi; aw1[olo + j] = lo;
        }
    }
    if (i >= 131072 && i < 393216) {          // AW2 (K=1024 concat)
        int i2 = i - 131072;
        int mt = i2 >> 11, rest = i2 & 2047, ks = rest >> 6, lane = rest & 63;
        int m = mt * 16 + (lane & 15);
        int u = m >> 2, g = m & 3;
        int kbase = ks * 32 + (lane >> 4) * 8;
        size_t ohi = ((((size_t)mt * 32 + ks) * 2 + 0) * 64 + lane) * 8;
        size_t olo = ((((size_t)mt * 32 + ks) * 2 + 1) * 64 + lane) * 8;
        #pragma unroll
        for (int j = 0; j < 8; ++j) {
            int k = kbase + j;
            float wv = (k < Hdim) ? W_ih2[(size_t)(g * Hdim + u) * Hdim + k]
                                  : W_hh2[(size_t)(g * Hdim + u) * Hdim + (k - Hdim)];
            f16 hi = (f16)wv;
            f16 lo = (f16)(wv - (float)hi);
            aw2[ohi + j] = hi; aw2[olo + j] = lo;
        }
    }
    if (i < Hdim) {
        float4 bb1 = { b_ih1[i] + b_hh1[i],               b_ih1[Hdim+i] + b_hh1[Hdim+i],
                       b_ih1[2*Hdim+i] + b_hh1[2*Hdim+i], b_ih1[3*Hdim+i] + b_hh1[3*Hdim+i] };
        float4 bb2 = { b_ih2[i] + b_hh2[i],               b_ih2[Hdim+i] + b_hh2[Hdim+i],
                       b_ih2[2*Hdim+i] + b_hh2[2*Hdim+i], b_ih2[3*Hdim+i] + b_hh2[3*Hdim+i] };
        float4 wx  = { W_ih1[i], W_ih1[Hdim+i], W_ih1[2*Hdim+i], W_ih1[3*Hdim+i] };
        ((float4*)(ws + B1P_OFF))[i] = bb1;
        ((float4*)(ws + B2P_OFF))[i] = bb2;
        ((float4*)(ws + WX1_OFF))[i] = wx;
    }
    if (i < Tdim * Bdim) {
        int t = i >> 7, b = i & 127;
        ws[XT_OFF + i] = x[b * Tdim + t];
    }
    if (i < 131072) {
        ((ull*)(ws + H1P_OFF))[i] = 0;
        ((ull*)(ws + H2P_OFF))[i] = 0;
    }
    if (i < 256) ((unsigned*)(ws + ARR_OFF))[i] = 0u;
}

// ---------- persistent MFMA main kernel (fence-free, LLC-direct h path) ----------
__global__ __launch_bounds__(256, 1) void lstm_main(float* ws,
                                                    const float* __restrict__ Wout,
                                                    const float* __restrict__ bout,
                                                    float* __restrict__ out) {
    const int tid  = threadIdx.x, bid = blockIdx.x;
    const int w    = tid >> 6;
    const int lane = tid & 63;
    const int quad = lane >> 4;
    const int col  = lane & 15;
    const bool is1  = (bid < NB1);
    const bool is2  = (bid >= NB1) && (bid < NB1 + NB2);
    const bool isout = (bid >= NB1 + NB2);

    __shared__ f16   awlds[65536];       // 128 KB weight A-fragments
    __shared__ float wout_lds[Hdim];
    __shared__ float psum[2][128];
    __shared__ float xflds[128];
    __shared__ float qpart[4][64];
    __shared__ ull   hstg[1024];         // 8 KB coalesced-store staging

    unsigned* flg = (unsigned*)(ws + ARR_OFF);   // f1@0(32) f2@64(64) fo@128(2)
    unsigned short* stg = (unsigned short*)hstg;
    const float* xT = ws + XT_OFF;
    const float bout0 = bout[0];

    // ---- waits: poll flags (relaxed agent loads). NO hardware fence — all h reads
    // are LLC-direct atomics, ordered after the poll by the dependent branch.
    auto wait1 = [&](unsigned T1) {
        if (tid < 64) {
            for (;;) {
                unsigned v1 = (lane < 32) ? cohloadu(flg + lane) : 0xFFFFFFFFu;
                if (__all(v1 >= T1)) break;
                __builtin_amdgcn_s_sleep(1);
            }
        }
        asm volatile("" ::: "memory");
        __syncthreads();
    };
    auto wait2o = [&](unsigned T2, unsigned To) {
        if (tid < 64) {
            for (;;) {
                unsigned v2 =              cohloadu(flg + 64 + lane);
                unsigned vo = (lane < 2) ? cohloadu(flg + 128 + lane) : 0xFFFFFFFFu;
                if (__all(v2 >= T2 && vo >= To)) break;
                __builtin_amdgcn_s_sleep(1);
            }
        }
        asm volatile("" ::: "memory");
        __syncthreads();
    };
    auto wait3 = [&](unsigned T1, unsigned T2, unsigned To) {
        if (tid < 64) {
            const unsigned sent = 0xFFFFFFFFu;
            for (;;) {
                unsigned v1 = (lane < 32) ? cohloadu(flg + lane)       : sent;
                unsigned v2 =               cohloadu(flg + 64 + lane);
                unsigned vo = (lane < 2)  ? cohloadu(flg + 128 + lane) : sent;
                if (__all(v1 >= T1 && v2 >= T2 && vo >= To)) break;
                __builtin_amdgcn_s_sleep(1);
            }
        }
        asm volatile("" ::: "memory");
        __syncthreads();
    };
    auto post = [&](unsigned* slot, unsigned val) {    // drain stores then own-slot store
        __syncthreads();
        if (tid == 0)
            __hip_atomic_store(slot, val, __ATOMIC_RELAXED, __HIP_MEMORY_SCOPE_AGENT);
    };

    // fragment planes as ull pointers (all reads via fragload -> LLC-direct)
    auto h1pu = [&](int par, int spl) {
        return (const ull*)(ws + H1P_OFF) + (size_t)(par*2+spl) * 16384; };
    auto h2pu = [&](int par, int spl) {
        return (const ull*)(ws + H2P_OFF) + (size_t)(par*2+spl) * 16384; };
    auto h1ull = [&](int par, int spl) {
        return (ull*)(ws + H1P_OFF) + (size_t)(par*2+spl) * 16384; };
    auto h2ull = [&](int par, int spl) {
        return (ull*)(ws + H2P_OFF) + (size_t)(par*2+spl) * 16384; };

    // ---- one-time: weight slice -> LDS
    if (!isout) {
        half8* d = (half8*)awlds;
        const half8* s = (const half8*)(ws + (is1 ? AW1_OFF : AW2_OFF))
                       + (size_t)(is1 ? bid : bid - NB1) * 8192;
        for (int i = tid; i < 8192; i += 256) d[i] = s[i];
    }
    wout_lds[tid]       = Wout[tid];
    wout_lds[256 + tid] = Wout[256 + tid];
    __syncthreads();
    const half8* aw8 = (const half8*)awlds;

    int b_[2] = { w * 32 + col, w * 32 + 16 + col };
    const int nt0 = 2 * w, nt1 = 2 * w + 1;
    int   u_[4];  float4 b1v[4], wxv[4];  float c1s[4][2];
    int   u2_[2]; float4 b2v[2];          float c2s[2][2];
    const int ks1 = bid >> 1, q0 = (bid & 1) * 2;            // G1 store geometry
    const int gid = bid - NB1;
    const int ks2 = gid >> 2, qg = gid & 3;                  // G2 store geometry
    if (is1) {
        #pragma unroll
        for (int mt = 0; mt < 4; ++mt) {
            u_[mt]  = bid * 16 + mt * 4 + quad;
            b1v[mt] = ((const float4*)(ws + B1P_OFF))[u_[mt]];
            wxv[mt] = ((const float4*)(ws + WX1_OFF))[u_[mt]];
            c1s[mt][0] = c1s[mt][1] = 0.0f;
        }
    } else if (is2) {
        #pragma unroll
        for (int mt = 0; mt < 2; ++mt) {
            u2_[mt] = gid * 8 + mt * 4 + quad;
            b2v[mt] = ((const float4*)(ws + B2P_OFF))[u2_[mt]];
            c2s[mt][0] = c2s[mt][1] = 0.0f;
        }
    }

    // ---- G1 coalesced publish: stage LDS -> 4 b64 agent stores/thread
    auto store1 = [&](int dpar) {
        __syncthreads();                                     // staging visible
        #pragma unroll
        for (int k = 0; k < 4; ++k) {
            int f = k * 256 + tid;                           // 0..1023 flat ull
            int spl = f >> 9, rest = f & 511, ntg = rest >> 6, pos = rest & 63;
            cohstore64(h1ull(dpar, spl) + ((ntg*16 + ks1)*64 + q0*16)*2 + pos, hstg[f]);
        }
    };
    auto stage1 = [&](int mt, int ntl, float hv) {
        f16 hhi = (f16)hv;
        f16 hlo = (f16)(hv - (float)hhi);
        int ntg = 2*w + ntl, mq = mt*4 + quad;
        int idx = ((ntg*32) + (mq>>3)*16 + col)*8 + (mq&7);
        stg[idx]        = __builtin_bit_cast(unsigned short, hhi);
        stg[2048 + idx] = __builtin_bit_cast(unsigned short, hlo);
    };

    // ---- layer-1 step: gates = Whi·hhi + Wlo·hhi + Whi·hlo + wx·x + b1
    auto gemm1 = [&](int spar, int dpar, float xv0, float xv1) {
        f32x4 acc[4][2] = {};
        const ull* fh = h1pu(spar, 0);
        const ull* fl = h1pu(spar, 1);
        half8 bh[8][2], bl[8][2];
        #pragma unroll
        for (int ks = 0; ks < 8; ++ks) {
            bh[ks][0] = fragload(fh + ((nt0*16+ks)*64 + lane)*2);
            bh[ks][1] = fragload(fh + ((nt1*16+ks)*64 + lane)*2);
            bl[ks][0] = fragload(fl + ((nt0*16+ks)*64 + lane)*2);
            bl[ks][1] = fragload(fl + ((nt1*16+ks)*64 + lane)*2);
        }
        #pragma unroll
        for (int ks = 0; ks < 16; ++ks) {
            half8 b0h = bh[ks&7][0], b1h = bh[ks&7][1];
            half8 b0l = bl[ks&7][0], b1l = bl[ks&7][1];
            if (ks < 8) {
                int kp = ks + 8;
                bh[ks&7][0] = fragload(fh + ((nt0*16+kp)*64 + lane)*2);
                bh[ks&7][1] = fragload(fh + ((nt1*16+kp)*64 + lane)*2);
                bl[ks&7][0] = fragload(fl + ((nt0*16+kp)*64 + lane)*2);
                bl[ks&7][1] = fragload(fl + ((nt1*16+kp)*64 + lane)*2);
            }
            #pragma unroll
            for (int mt = 0; mt < 4; ++mt) {
                half8 ah = aw8[((mt*16 + ks)*2 + 0)*64 + lane];
                half8 al = aw8[((mt*16 + ks)*2 + 1)*64 + lane];
                acc[mt][0] = __builtin_amdgcn_mfma_f32_16x16x32_f16(ah, b0h, acc[mt][0], 0, 0, 0);
                acc[mt][0] = __builtin_amdgcn_mfma_f32_16x16x32_f16(al, b0h, acc[mt][0], 0, 0, 0);
                acc[mt][0] = __builtin_amdgcn_mfma_f32_16x16x32_f16(ah, b0l, acc[mt][0], 0, 0, 0);
                acc[mt][1] = __builtin_amdgcn_mfma_f32_16x16x32_f16(ah, b1h, acc[mt][1], 0, 0, 0);
                acc[mt][1] = __builtin_amdgcn_mfma_f32_16x16x32_f16(al, b1h, acc[mt][1], 0, 0, 0);
                acc[mt][1] = __builtin_amdgcn_mfma_f32_16x16x32_f16(ah, b1l, acc[mt][1], 0, 0, 0);
            }
        }
        float xv[2] = { xv0, xv1 };
        #pragma unroll
        for (int mt = 0; mt < 4; ++mt)
            #pragma unroll
            for (int nt = 0; nt < 2; ++nt) {
                f32x4 g = acc[mt][nt];
                float pi = g[0] + b1v[mt].x + wxv[mt].x * xv[nt];
                float pf = g[1] + b1v[mt].y + wxv[mt].y * xv[nt];
                float pg = g[2] + b1v[mt].z + wxv[mt].z * xv[nt];
                float po = g[3] + b1v[mt].w + wxv[mt].w * xv[nt];
                float c = fmaf(sigm(pf), c1s[mt][nt], sigm(pi) * tanh_fast(pg));
                c1s[mt][nt] = c;
                stage1(mt, nt, sigm(po) * tanh_fast(c));
            }
        store1(dpar);
    };

    // ---- layer-2 step with cross-wait prefetch ----
    auto g2_step = [&](int s) {
        int cpar = s & 3, ppar = (s - 1) & 3;
        const ull* fh = h1pu(cpar, 0);
        const ull* fl = h1pu(cpar, 1);
        const ull* gh = h2pu(ppar, 0);
        const ull* gl = h2pu(ppar, 1);

        wait1((unsigned)(s + 1));                   // h1(s) published (usually instant)
        half8 bh[8][2], bl[8][2];
        #pragma unroll
        for (int ks = 0; ks < 8; ++ks) {            // prefetch h1-half first batch
            bh[ks][0] = fragload(fh + ((nt0*16+ks)*64 + lane)*2);
            bh[ks][1] = fragload(fh + ((nt1*16+ks)*64 + lane)*2);
            bl[ks][0] = fragload(fl + ((nt0*16+ks)*64 + lane)*2);
            bl[ks][1] = fragload(fl + ((nt1*16+ks)*64 + lane)*2);
        }
        wait2o((unsigned)s, (s >= 4) ? (unsigned)(s - 3) : 0u);   // real wait

        f32x4 acc[2][2] = {};
        #pragma unroll
        for (int ks = 0; ks < 32; ++ks) {
            half8 b0h = bh[ks&7][0], b1h = bh[ks&7][1];
            half8 b0l = bl[ks&7][0], b1l = bl[ks&7][1];
            if (ks < 24) {
                int kp = ks + 8;
                const ull* sh = (kp < 16) ? fh : gh;
                const ull* sl = (kp < 16) ? fl : gl;
                int kq = (kp < 16) ? kp : kp - 16;
                bh[ks&7][0] = fragload(sh + ((nt0*16+kq)*64 + lane)*2);
                bh[ks&7][1] = fragload(sh + ((nt1*16+kq)*64 + lane)*2);
                bl[ks&7][0] = fragload(sl + ((nt0*16+kq)*64 + lane)*2);
                bl[ks&7][1] = fragload(sl + ((nt1*16+kq)*64 + lane)*2);
            }
            #pragma unroll
            for (int mt = 0; mt < 2; ++mt) {
                half8 ah = aw8[((mt*32 + ks)*2 + 0)*64 + lane];
                half8 al = aw8[((mt*32 + ks)*2 + 1)*64 + lane];
                acc[mt][0] = __builtin_amdgcn_mfma_f32_16x16x32_f16(ah, b0h, acc[mt][0], 0, 0, 0);
                acc[mt][0] = __builtin_amdgcn_mfma_f32_16x16x32_f16(al, b0h, acc[mt][0], 0, 0, 0);
                acc[mt][0] = __builtin_amdgcn_mfma_f32_16x16x32_f16(ah, b0l, acc[mt][0], 0, 0, 0);
                acc[mt][1] = __builtin_amdgcn_mfma_f32_16x16x32_f16(ah, b1h, acc[mt][1], 0, 0, 0);
                acc[mt][1] = __builtin_amdgcn_mfma_f32_16x16x32_f16(al, b1h, acc[mt][1], 0, 0, 0);
                acc[mt][1] = __builtin_amdgcn_mfma_f32_16x16x32_f16(ah, b1l, acc[mt][1], 0, 0, 0);
            }
        }
        // epilogue: stage hi/lo then coalesced publish (2 b64 stores/thread)
        #pragma unroll
        for (int mt = 0; mt < 2; ++mt)
            #pragma unroll
            for (int nt = 0; nt < 2; ++nt) {
                f32x4 g = acc[mt][nt];
                float pi = g[0] + b2v[mt].x;
                float pf = g[1] + b2v[mt].y;
                float pg = g[2] + b2v[mt].z;
                float po = g[3] + b2v[mt].w;
                float c = fmaf(sigm(pf), c2s[mt][nt], sigm(pi) * tanh_fast(pg));
                c2s[mt][nt] = c;
                float hv = sigm(po) * tanh_fast(c);
                f16 hhi = (f16)hv;
                f16 hlo = (f16)(hv - (float)hhi);
                int ntg = 2*w + nt, mq = mt*4 + quad;
                int idx = ((ntg*16) + col)*8 + mq;
                stg[idx]        = __builtin_bit_cast(unsigned short, hhi);
                stg[1024 + idx] = __builtin_bit_cast(unsigned short, hlo);
            }
        __syncthreads();
        #pragma unroll
        for (int k = 0; k < 2; ++k) {
            int f = k * 256 + tid;                           // 0..511 flat ull
            int spl = f >> 8, rest = f & 255, ntg = rest >> 5, pos = rest & 31;
            cohstore64(h2ull(cpar, spl) + ((ntg*16 + ks2)*64 + qg*16)*2 + pos, hstg[f]);
        }
        post(&flg[64 + gid], (unsigned)(s + 1));
    };

    // ================= GROUP 1 =================
    if (is1) {
        // prologue: h1(0) from x(0) (h1(-1)=0) -> parity 0
        #pragma unroll
        for (int mt = 0; mt < 4; ++mt)
            #pragma unroll
            for (int nt = 0; nt < 2; ++nt) {
                float xv = xT[b_[nt]];
                float pi = b1v[mt].x + wxv[mt].x * xv;
                float pg = b1v[mt].z + wxv[mt].z * xv;
                float po = b1v[mt].w + wxv[mt].w * xv;
                float c = sigm(pi) * tanh_fast(pg);
                c1s[mt][nt] = c;
                stage1(mt, nt, sigm(po) * tanh_fast(c));
            }
        store1(0);
        post(&flg[bid], 1u);

        // main: step t publishes h1(t+1); f1 -> t+2
        for (int t = 0; t <= Tdim - 2; ++t) {
            wait3((unsigned)(t + 1), (t >= 3) ? (unsigned)(t - 2) : 0u, 0u);
            gemm1(t & 3, (t + 1) & 3,
                  xT[(t + 1) * Bdim + b_[0]], xT[(t + 1) * Bdim + b_[1]]);
            post(&flg[bid], (unsigned)(t + 2));
        }

        // future: step t computes feedback O(t-1), publishes h1(t)
        for (int t = Tdim; t < TT; ++t) {
            wait3((unsigned)t, (unsigned)t, 0u);
            {
                int b = tid & 127, kh = tid >> 7;
                int nt = b >> 4, nl = b & 15;
                const ull* ph = h2pu((t - 1) & 3, 0);
                const ull* pl = h2pu((t - 1) & 3, 1);
                float a = 0.0f;
                #pragma unroll
                for (int kk = 0; kk < 8; ++kk) {
                    int ks = kh * 8 + kk;
                    #pragma unroll
                    for (int qd = 0; qd < 4; ++qd) {
                        half8 vh = fragload(ph + ((nt*16+ks)*64 + qd*16 + nl)*2);
                        half8 vl = fragload(pl + ((nt*16+ks)*64 + qd*16 + nl)*2);
                        int ub = ks*32 + qd*8;
                        #pragma unroll
                        for (int j = 0; j < 8; ++j)
                            a = fmaf((float)vh[j] + (float)vl[j], wout_lds[ub + j], a);
                    }
                }
                psum[kh][b] = a;
                __syncthreads();
                if (tid < 128) xflds[tid] = psum[0][tid] + psum[1][tid] + bout0;
                __syncthreads();
            }
            gemm1((t - 1) & 3, t & 3, xflds[b_[0]], xflds[b_[1]]);
            post(&flg[bid], (unsigned)(t + 1));
        }
    }
    // ================= GROUP 2 =================
    else if (is2) {
        for (int s = 0; s < TT; ++s) g2_step(s);
    }
    // ================= OUT blocks =================
    else {
        int b = (bid - NB1 - NB2) * 64 + lane;
        int nt = b >> 4, nl = b & 15;
        for (int s = 0; s < TT; ++s) {
            wait3(0u, (unsigned)(s + 1), 0u);
            const ull* ph = h2pu(s & 3, 0);
            const ull* pl = h2pu(s & 3, 1);
            float a = 0.0f;
            #pragma unroll
            for (int kk = 0; kk < 4; ++kk) {
                int ks = w * 4 + kk;
                #pragma unroll
                for (int qd = 0; qd < 4; ++qd) {
                    half8 vh = fragload(ph + ((nt*16+ks)*64 + qd*16 + nl)*2);
                    half8 vl = fragload(pl + ((nt*16+ks)*64 + qd*16 + nl)*2);
                    int ub = ks*32 + qd*8;
                    #pragma unroll
                    for (int j = 0; j < 8; ++j)
                        a = fmaf((float)vh[j] + (float)vl[j], wout_lds[ub + j], a);
                }
            }
            qpart[w][lane] = a;
            __syncthreads();
            if (w == 0)
                out[(size_t)b * TT + s] = qpart[0][lane] + qpart[1][lane]
                                        + qpart[2][lane] + qpart[3][lane] + bout0;
            post(&flg[128 + (bid - NB1 - NB2)], (unsigned)(s + 1));
        }
    }
}

extern "C" void kernel_launch(void* const* d_in, const int* in_sizes, int n_in,
                              void* d_out, int out_size, void* d_ws, size_t ws_size,
                              hipStream_t stream) {
    const float* x     = (const float*)d_in[0];
    const float* W_ih1 = (const float*)d_in[1];
    const float* W_hh1 = (const float*)d_in[2];
    const float* b_ih1 = (const float*)d_in[3];
    const float* b_hh1 = (const float*)d_in[4];
    const float* W_ih2 = (const float*)d_in[5];
    const float* W_hh2 = (const float*)d_in[6];
    const float* b_ih2 = (const float*)d_in[7];
    const float* b_hh2 = (const float*)d_in[8];
    const float* W_out = (const float*)d_in[9];
    const float* b_out = (const float*)d_in[10];
    float* ws  = (float*)d_ws;
    float* out = (float*)d_out;

    hipLaunchKernelGGL(lstm_prep, dim3(1536), dim3(256), 0, stream,
                       x, W_ih1, W_hh1, b_ih1, b_hh1, W_ih2, W_hh2, b_ih2, b_hh2, ws);
    hipLaunchKernelGGL(lstm_main, dim3(NBLK), dim3(256), 0, stream,
                       ws, W_out, b_out, out);
}